// Round 1
// baseline (292.215 us; speedup 1.0000x reference)
//
#include <hip/hip_runtime.h>
#include <math.h>

#define NEG_SLOPE 0.2f
#define LOG2E 1.4426950408889634f

typedef __attribute__((ext_vector_type(8))) short short8;   // 8 bf16 (4 VGPRs)
typedef __attribute__((ext_vector_type(4))) float f32x4;
typedef __attribute__((ext_vector_type(2))) float v2f;

__device__ __forceinline__ int imin(int a, int b) { return a < b ? a : b; }

__device__ __forceinline__ unsigned int f2bf(float f) {
    unsigned int u = __float_as_uint(f);
    return (u + 0x7fffu + ((u >> 16) & 1u)) >> 16;   // RNE
}
__device__ __forceinline__ float fast_exp2(float x) {
#if __has_builtin(__builtin_amdgcn_exp2f)
    return __builtin_amdgcn_exp2f(x);
#else
    return exp2f(x);
#endif
}
// fp8 (OCP e4m3 on gfx950) hardware pack/unpack
__device__ __forceinline__ unsigned char f2fp8(float v) {
    return (unsigned char)(__builtin_amdgcn_cvt_pk_fp8_f32(v, v, 0, false) & 0xff);
}
template <int CTRL>
__device__ __forceinline__ float dpp_add(float v) {
    int t = __builtin_amdgcn_update_dpp(0, __float_as_int(v), CTRL, 0xF, 0xF, true);
    return v + __int_as_float(t);
}

// ---------------------------------------------------------------------------
// Fused prep kernel: three disjoint index ranges in one launch.
//  [0, E)            : packed histogram (64-bit atomic, 64B-padded slots)
//  [E, E+nF4)        : x fp32 -> bf16 (vec4)
//  [E+nF4, ..+WTOT)  : weight transposes -> bf16 + bias concats
// ---------------------------------------------------------------------------
__global__ void fused_prep(const int* __restrict__ ei, const float* __restrict__ ea,
                           unsigned long long* __restrict__ hist, int E,
                           const float* __restrict__ x, unsigned short* __restrict__ xb, int nF4,
                           const float* __restrict__ W1l, const float* __restrict__ W1r,
                           const float* __restrict__ W2l, const float* __restrict__ W2r,
                           const float* __restrict__ b1l, const float* __restrict__ b1r,
                           const float* __restrict__ b2l, const float* __restrict__ b2r,
                           unsigned short* __restrict__ Wt1, unsigned short* __restrict__ Wt2,
                           float* __restrict__ b1cat, float* __restrict__ b2cat,
                           int F, int HC1, int HC2) {
    int i = blockIdx.x * blockDim.x + threadIdx.x;
    if (i < E) {
        int d = ei[E + i];
        long long fx = (long long)__float2int_rn(ea[i] * 65536.0f);
        unsigned long long v = ((unsigned long long)fx << 32) | 1ull;
        atomicAdd(&hist[(size_t)d * 8], v);
        return;
    }
    int j = i - E;
    if (j < nF4) {
        float4 v = ((const float4*)x)[j];
        uint2 r;
        r.x = f2bf(v.x) | (f2bf(v.y) << 16);
        r.y = f2bf(v.z) | (f2bf(v.w) << 16);
        ((uint2*)xb)[j] = r;
        return;
    }
    int k = j - nF4;
    int S1 = F * HC1, S2 = HC1 * HC2;
    if (k < S1) {
        int kk = k / HC1, nn = k - kk * HC1;
        Wt1[(size_t)nn * F + kk] = (unsigned short)f2bf(W1l[k]);
    } else if (k < 2 * S1) {
        int m = k - S1;
        int kk = m / HC1, nn = m - kk * HC1;
        Wt1[(size_t)(HC1 + nn) * F + kk] = (unsigned short)f2bf(W1r[m]);
    } else if (k < 2 * S1 + S2) {
        int m = k - 2 * S1;
        int kk = m / HC2, nn = m - kk * HC2;
        Wt2[(size_t)nn * HC1 + kk] = (unsigned short)f2bf(W2l[m]);
    } else if (k < 2 * S1 + 2 * S2) {
        int m = k - 2 * S1 - S2;
        int kk = m / HC2, nn = m - kk * HC2;
        Wt2[(size_t)(HC2 + nn) * HC1 + kk] = (unsigned short)f2bf(W2r[m]);
    } else if (k < 2 * S1 + 2 * S2 + 2 * HC1) {
        int m = k - 2 * S1 - 2 * S2;
        b1cat[m] = (m < HC1) ? b1l[m] : b1r[m - HC1];
    } else if (k < 2 * S1 + 2 * S2 + 2 * HC1 + 2 * HC2) {
        int m = k - 2 * S1 - 2 * S2 - 2 * HC1;
        b2cat[m] = (m < HC2) ? b2l[m] : b2r[m - HC2];
    }
}

// ---------------------------------------------------------------------------
// 2-phase parallel scan over hist (padded stride 8): scan_a computes raw
// block sums; scan_c derives its own prefix from bsum in-wave (scan_b folded).
// ---------------------------------------------------------------------------
__global__ void scan_a(const unsigned long long* __restrict__ hist, int* __restrict__ bsum, int n) {
    __shared__ int wred[4];
    int base = blockIdx.x * 1024;
    int tid = threadIdx.x;
    int s = 0;
#pragma unroll
    for (int k = 0; k < 4; ++k) {
        int i = base + tid + k * 256;
        if (i < n) s += (int)(hist[(size_t)i * 8] & 0xffffffffull);
    }
#pragma unroll
    for (int off = 32; off > 0; off >>= 1) s += __shfl_xor(s, off, 64);
    if ((tid & 63) == 0) wred[tid >> 6] = s;
    __syncthreads();
    if (tid == 0) bsum[blockIdx.x] = wred[0] + wred[1] + wred[2] + wred[3];
}

__global__ void scan_c(const unsigned long long* __restrict__ hist,
                       const int* __restrict__ bsum, int* __restrict__ row_ptr,
                       int* __restrict__ wptr_pad, float* __restrict__ ea_loop,
                       int n, int B) {
    __shared__ int wtot[4];
    __shared__ int sh_base;
    int tid = threadIdx.x;
    int wid = tid >> 6, lane = tid & 63;
    int i0 = blockIdx.x * 1024 + tid * 4;
    int dcnt[4]; float esum[4];
#pragma unroll
    for (int k = 0; k < 4; ++k) {
        if (i0 + k < n) {
            unsigned long long h = hist[(size_t)(i0 + k) * 8];
            dcnt[k] = (int)(h & 0xffffffffull);
            esum[k] = (float)((int)(h >> 32)) * (1.0f / 65536.0f);
        } else { dcnt[k] = 0; esum[k] = 0.0f; }
    }
    int tsum = dcnt[0] + dcnt[1] + dcnt[2] + dcnt[3];
    int s = tsum;
#pragma unroll
    for (int off = 1; off < 64; off <<= 1) {
        int t = __shfl_up(s, off, 64);
        if (lane >= off) s += t;
    }
    if (lane == 63) wtot[wid] = s;
    // wave 0: block prefix (sum of bsum[0..blockIdx)) and grand total
    if (tid < 64) {
        int v   = (tid < B) ? bsum[tid] : 0;
        int pre = (tid < (int)blockIdx.x) ? v : 0;
        int tot = v;
#pragma unroll
        for (int off = 32; off > 0; off >>= 1) {
            pre += __shfl_xor(pre, off, 64);
            tot += __shfl_xor(tot, off, 64);
        }
        if (tid == 0) {
            sh_base = pre;
            if (blockIdx.x == 0) row_ptr[n] = tot;
        }
    }
    __syncthreads();
    int wpre = 0;
#pragma unroll
    for (int k = 0; k < 4; ++k) if (k < wid) wpre += wtot[k];
    int pre = sh_base + wpre + (s - tsum);
    if (i0 < n) {
        int4 e;
        e.x = pre;
        e.y = pre + dcnt[0];
        e.z = e.y + dcnt[1];
        e.w = e.z + dcnt[2];
        *(int4*)(row_ptr + i0) = e;
        int ev[4] = { e.x, e.y, e.z, e.w };
        float4 el;
        el.x = esum[0] / fmaxf((float)dcnt[0], 1.0f);
        el.y = esum[1] / fmaxf((float)dcnt[1], 1.0f);
        el.z = esum[2] / fmaxf((float)dcnt[2], 1.0f);
        el.w = esum[3] / fmaxf((float)dcnt[3], 1.0f);
        *(float4*)(ea_loop + i0) = el;
#pragma unroll
        for (int k = 0; k < 4; ++k) wptr_pad[(size_t)(i0 + k) * 16] = ev[k];
    }
}

// ---------------------------------------------------------------------------
// scatter edges into CSR order; (src,w) packed as int2.
// ---------------------------------------------------------------------------
__global__ void edge_scatter(const int* __restrict__ ei, const float* __restrict__ ea,
                             int* __restrict__ wptr_pad, int2* __restrict__ spk, int E) {
    int e = blockIdx.x * blockDim.x + threadIdx.x;
    if (e < E) {
        int d = ei[E + e];
        int pos = atomicAdd(&wptr_pad[(size_t)d * 16], 1);
        spk[pos] = make_int2(ei[e], __float_as_int(ea[e]));
    }
}

// ---------------------------------------------------------------------------
// bf16 MFMA GEMM + bias (B pre-transposed), 64x64 tile, BK=32.
// OUT_FP8: epilogue packs to fp8 (e4m3, hardware RNE) else bf16.
// ---------------------------------------------------------------------------
template <bool OUT_FP8>
__global__ void __launch_bounds__(256)
gemm_bf16(const unsigned short* __restrict__ A, const unsigned short* __restrict__ Bt,
          const float* __restrict__ bias, void* __restrict__ Cv,
          int M, int N, int K) {
    __shared__ __attribute__((aligned(16))) unsigned short As[64 * 40];
    __shared__ __attribute__((aligned(16))) unsigned short Bs[64 * 40];
    int tid  = threadIdx.x;
    int wave = tid >> 6, lane = tid & 63;
    int m0 = blockIdx.x * 64, n0 = blockIdx.y * 64;
    int row = tid >> 2, kg = (tid & 3) * 8;

    f32x4 acc[4] = {};
    for (int kk = 0; kk < K; kk += 32) {
        int gm = m0 + row;
        uint4 av;
        if (gm < M) av = *(const uint4*)(A + (size_t)gm * K + kk + kg);
        else        av = make_uint4(0, 0, 0, 0);
        *(uint4*)&As[row * 40 + kg] = av;
        uint4 bv = *(const uint4*)(Bt + (size_t)(n0 + row) * K + kk + kg);
        *(uint4*)&Bs[row * 40 + kg] = bv;
        __syncthreads();
        short8 a = *(const short8*)&As[(wave * 16 + (lane & 15)) * 40 + (lane >> 4) * 8];
#pragma unroll
        for (int g = 0; g < 4; ++g) {
            short8 b = *(const short8*)&Bs[(g * 16 + (lane & 15)) * 40 + (lane >> 4) * 8];
            acc[g] = __builtin_amdgcn_mfma_f32_16x16x32_bf16(a, b, acc[g], 0, 0, 0);
        }
        __syncthreads();
    }
#pragma unroll
    for (int g = 0; g < 4; ++g) {
        int col = n0 + g * 16 + (lane & 15);
        float bs = bias[col];
#pragma unroll
        for (int r = 0; r < 4; ++r) {
            int grow = m0 + wave * 16 + (lane >> 4) * 4 + r;
            if (grow < M) {
                float val = acc[g][r] + bs;
                if constexpr (OUT_FP8) {
                    ((unsigned char*)Cv)[(size_t)grow * N + col] = f2fp8(val);
                } else {
                    ((unsigned short*)Cv)[(size_t)grow * N + col] = (unsigned short)f2bf(val);
                }
            }
        }
    }
}

// ---------------------------------------------------------------------------
// helpers for gat_agg (fp8 gather, packed-f32 math)
// ---------------------------------------------------------------------------
template <int NG>
__device__ __forceinline__ void unp2(uint2 u, v2f* xf) {
    xf[0] = __builtin_amdgcn_cvt_pk_f32_fp8(u.x, false);
    xf[1] = __builtin_amdgcn_cvt_pk_f32_fp8(u.x, true);
    if constexpr (NG == 4) {
        xf[2] = __builtin_amdgcn_cvt_pk_f32_fp8(u.y, false);
        xf[3] = __builtin_amdgcn_cvt_pk_f32_fp8(u.y, true);
    }
}
// reduction over G lanes, confined within each 32-lane half-wave
template <int G>
__device__ __forceinline__ float grp_reduce32(float vs) {
    vs = dpp_add<0xB1>(vs);                               // xor 1
    if constexpr (G >= 4)  vs = dpp_add<0x4E>(vs);        // xor 2
    if constexpr (G >= 8)  vs = dpp_add<0x141>(vs);       // xor 4 (row_half_mirror)
    if constexpr (G >= 16) vs = dpp_add<0x140>(vs);       // xor 8 (row_mirror)
    if constexpr (G >= 32) {                              // xor 16 (within 32-group)
        int t = __builtin_amdgcn_ds_swizzle(__float_as_int(vs), 0x401F);
        vs += __int_as_float(t);
    }
    return vs;
}

// ---------------------------------------------------------------------------
// fused GATv2 gather(fp8) + score + softmax + aggregate + relu.
// TWO EDGES PER WAVE: lanes 0-31 process edge A, lanes 32-63 edge B; each lane
// covers NV = HC/32 channels (layer1: 8, layer2: 4). Channel math is float2
// (v_pk_fma_f32/v_pk_add_f32); leaky-relu folded as att6*(mm + (2/3)|mm|)
// with |mm| a free VOP3 abs modifier. Per-edge overhead (readlanes, reduce,
// exp, gather instruction) is halved vs wave-per-edge. Cross-half combine of
// (l, o) is one shfl_xor(32) per accumulator at node end. Mov-free
// double-buffered pair pipeline (2 pairs = 4 edges in flight per group).
// OUT_MODE 0: dense bf16 rows.  OUT_MODE 1: fused pooling into partial slots.
// ---------------------------------------------------------------------------
template <int HC, int STRIDE, int C, int OUT_MODE>
__global__ void __launch_bounds__(256)
gat_agg(const unsigned char* __restrict__ xlr,
        const float* __restrict__ We, const float* __restrict__ att,
        const float* __restrict__ bias,
        const int* __restrict__ row_ptr, const int2* __restrict__ spk,
        const float* __restrict__ ea_loop,
        void* __restrict__ out, int n) {
    constexpr int NV = HC / 32;      // channels (bytes) per lane (half-wave covers row)
    constexpr int NG = NV / 2;       // float2 groups per lane
    constexpr int G  = C / NV;       // lanes per head within a half-wave
    constexpr float K23 = 2.0f / 3.0f;
    int wave = threadIdx.x >> 6;
    int lane = threadIdx.x & 63;
    int node = blockIdx.x * 4 + wave;
    if (node >= n) return;
    unsigned int lo32 = (unsigned int)(lane & 31) * NV;   // channel/byte offset

    auto ldd = [&](unsigned int off) -> uint2 {
        uint2 r;
        if constexpr (NV == 8) r = *(const uint2*)(xlr + off);
        else { r.x = *(const unsigned int*)(xlr + off); r.y = 0u; }
        return r;
    };

    v2f xr2[NG], We2[NG], att62[NG], o2[NG];
    {
        uint2 xru = ldd((unsigned int)node * STRIDE + HC + lo32);
        unp2<NG>(xru, xr2);
    }
#pragma unroll
    for (int g = 0; g < NG; ++g) {
        We2[g]   = *(const v2f*)(We  + lo32 + 2 * g);
        v2f a    = *(const v2f*)(att + lo32 + 2 * g);
        att62[g] = a * (0.6f * LOG2E);
        o2[g]    = v2f{0.0f, 0.0f};
    }
    float l = 0.0f;

    int start = __builtin_amdgcn_readfirstlane(row_ptr[node]);
    int end   = __builtin_amdgcn_readfirstlane(row_ptr[node + 1]);
    float ea_l = ea_loop[node];

    auto process = [&](uint2 du, float w, bool maskhi) {
        v2f xf[NG];
        unp2<NG>(du, xf);
        v2f vs2 = v2f{0.0f, 0.0f};
#pragma unroll
        for (int g = 0; g < NG; ++g) {
            v2f t  = We2[g] * w + xr2[g];        // v_pk_fma_f32
            v2f mm = xf[g] + t;                  // v_pk_add_f32
            v2f u;
            u.x = fmaf(fabsf(mm.x), K23, mm.x);  // abs = free src modifier
            u.y = fmaf(fabsf(mm.y), K23, mm.y);
            vs2 = att62[g] * u + vs2;            // v_pk_fma_f32
        }
        float vs = vs2.x + vs2.y;
        vs = grp_reduce32<G>(vs);
        float pr = fast_exp2(vs);
        if (maskhi && lane >= 32) pr = 0.0f;
        l += pr;
#pragma unroll
        for (int g = 0; g < NG; ++g) o2[g] = xf[g] * pr + o2[g];  // v_pk_fma_f32
    };

    // ---- self-loop edge (both halves compute same edge; upper half masked) ----
    process(ldd((unsigned int)node * STRIDE + lo32), ea_l, true);

    // ---- real edges: batches of 64, pairs across half-waves, double-buffered ----
    int cnt = end - start;
    for (int b0 = 0; b0 < cnt; b0 += 64) {
        int rem = imin(64, cnt - b0);
        int idxc = imin(start + b0 + lane, end - 1);
        int2 pv = spk[idxc];

        auto ldp = [&](int p) -> uint2 {   // gather for pair p (edges 2p, 2p+1)
            int sA = __builtin_amdgcn_readlane(pv.x, 2 * p);
            int sB = __builtin_amdgcn_readlane(pv.x, 2 * p + 1);
            int s  = (lane < 32) ? sA : sB;
            return ldd((unsigned int)s * STRIDE + lo32);
        };
        auto ldw = [&](int p) -> float {
            int wA = __builtin_amdgcn_readlane(pv.y, 2 * p);
            int wB = __builtin_amdgcn_readlane(pv.y, 2 * p + 1);
            return __int_as_float((lane < 32) ? wA : wB);
        };

        int npair = rem >> 1;
        if (npair > 0) {
            int pc = npair - 1;
            uint2 A0 = ldp(0), A1 = ldp(imin(1, pc));
            float Wa0 = ldw(0), Wa1 = ldw(imin(1, pc));
            int p = 0;
            for (; p + 4 <= npair; p += 4) {
                // load group B (pairs p+2, p+3 — guaranteed in range)
                uint2 B0 = ldp(p + 2), B1 = ldp(p + 3);
                float Wb0 = ldw(p + 2), Wb1 = ldw(p + 3);
                // process group A (pairs p, p+1)
                process(A0, Wa0, false); process(A1, Wa1, false);
                // reload group A (pairs p+4, p+5, clamped)
                A0 = ldp(imin(p + 4, pc)); A1 = ldp(imin(p + 5, pc));
                Wa0 = ldw(imin(p + 4, pc)); Wa1 = ldw(imin(p + 5, pc));
                // process group B
                process(B0, Wb0, false); process(B1, Wb1, false);
            }
            int left = npair - p;
            if (left > 0) process(A0, Wa0, false);
            if (left > 1) process(A1, Wa1, false);
            for (int k = p + 2; k < npair; ++k) process(ldp(k), ldw(k), false);
        }
        if (rem & 1) {   // odd tail edge: both halves same edge, upper masked
            int e = rem - 1;
            int s = __builtin_amdgcn_readlane(pv.x, e);
            float w = __int_as_float(__builtin_amdgcn_readlane(pv.y, e));
            process(ldd((unsigned int)s * STRIDE + lo32), w, true);
        }
    }

    // ---- combine the two half-wave accumulators (all lanes active) ----
    l += __shfl_xor(l, 32, 64);
#pragma unroll
    for (int g = 0; g < NG; ++g) {
        o2[g].x += __shfl_xor(o2[g].x, 32, 64);
        o2[g].y += __shfl_xor(o2[g].y, 32, 64);
    }
    float inv = 1.0f / (l + 1e-16f);

    if (lane < 32) {
        float v[NV];
#pragma unroll
        for (int g = 0; g < NG; ++g) {
            v2f b = *(const v2f*)(bias + lo32 + 2 * g);
            v[2 * g]     = fmaxf(o2[g].x * inv + b.x, 0.0f);
            v[2 * g + 1] = fmaxf(o2[g].y * inv + b.y, 0.0f);
        }
        if constexpr (OUT_MODE == 0) {
            // dense bf16 rows (h1)
            unsigned short* op = (unsigned short*)out + (size_t)node * HC + lo32;
            if constexpr (NV == 8) {
                uint4 t;
                t.x = f2bf(v[0]) | (f2bf(v[1]) << 16);
                t.y = f2bf(v[2]) | (f2bf(v[3]) << 16);
                t.z = f2bf(v[4]) | (f2bf(v[5]) << 16);
                t.w = f2bf(v[6]) | (f2bf(v[7]) << 16);
                *(uint4*)op = t;
            } else {
                uint2 t;
                t.x = f2bf(v[0]) | (f2bf(v[1]) << 16);
                t.y = f2bf(v[2]) | (f2bf(v[3]) << 16);
                *(uint2*)op = t;
            }
        } else {
            // fused pooling: accumulate relu'd row into partial slot
            float* pacc = (float*)out + (size_t)(blockIdx.x & 255) * 128 + lo32;
#pragma unroll
            for (int j = 0; j < NV; ++j) atomicAdd(&pacc[j], v[j]);
        }
    }
}

// ---------------------------------------------------------------------------
// finish pooling, softmax over 128, sigmoid(alpha). 1024 threads.
// ---------------------------------------------------------------------------
__global__ void __launch_bounds__(1024)
pool_final(const float* __restrict__ partial, int nb,
           const float* __restrict__ alpha_in,
           float* __restrict__ out, int n) {
    __shared__ float acc[8][128];
    __shared__ float red[4];
    int t = threadIdx.x & 127;        // column
    int g = threadIdx.x >> 7;         // group 0..7
    float s = 0.0f;
    for (int b = g; b < nb; b += 8) s += partial[b * 128 + t];
    acc[g][t] = s;
    __syncthreads();
    if (threadIdx.x < 128) {
        float tot = 0.0f;
#pragma unroll
        for (int k = 0; k < 8; ++k) tot += acc[k][t];
        float mean = tot / (float)n;
        float mx = mean;
#pragma unroll
        for (int off = 32; off > 0; off >>= 1) mx = fmaxf(mx, __shfl_xor(mx, off, 64));
        if ((t & 63) == 0) red[t >> 6] = mx;
        __syncthreads();
        mx = fmaxf(red[0], red[1]);
        float ex = __expf(mean - mx);
        float sm = ex;
#pragma unroll
        for (int off = 32; off > 0; off >>= 1) sm += __shfl_xor(sm, off, 64);
        if ((t & 63) == 0) red[2 + (t >> 6)] = sm;
        __syncthreads();
        sm = red[2] + red[3];
        out[t] = ex / sm;
        if (t == 0) out[128] = 1.0f / (1.0f + __expf(-alpha_in[0]));
    }
}

// ---------------------------------------------------------------------------
extern "C" void kernel_launch(void* const* d_in, const int* in_sizes, int n_in,
                              void* d_out, int out_size, void* d_ws, size_t ws_size,
                              hipStream_t stream) {
    const float* x    = (const float*)d_in[0];
    const int*   ei   = (const int*)d_in[1];
    const float* ea   = (const float*)d_in[2];
    const float* W1l  = (const float*)d_in[3];
    const float* b1l  = (const float*)d_in[4];
    const float* W1r  = (const float*)d_in[5];
    const float* b1r  = (const float*)d_in[6];
    const float* We1  = (const float*)d_in[7];
    const float* att1 = (const float*)d_in[8];
    const float* bias1= (const float*)d_in[9];
    const float* W2l  = (const float*)d_in[10];
    const float* b2l  = (const float*)d_in[11];
    const float* W2r  = (const float*)d_in[12];
    const float* b2r  = (const float*)d_in[13];
    const float* We2  = (const float*)d_in[14];
    const float* att2 = (const float*)d_in[15];
    const float* bias2= (const float*)d_in[16];
    const float* alpha= (const float*)d_in[17];
    float* out = (float*)d_out;

    const int F = 128, HC1 = 256, HC2 = 128;
    const int n = in_sizes[0] / F;       // 20000
    const int E = in_sizes[1] / 2;       // 640000
    const int B = (n + 1023) / 1024;     // scan blocks

    char* ws = (char*)d_ws;
    size_t off = 0;
    auto alloc = [&](size_t bytes) { size_t p = off; off += (bytes + 255) & ~(size_t)255; return p; };

    unsigned long long* hist = (unsigned long long*)(ws + alloc((size_t)n * 8 * 8));  // padded x8
    int*   row_ptr = (int*)  (ws + alloc((size_t)(n + 1) * 4));
    int*   wptr    = (int*)  (ws + alloc((size_t)n * 16 * 4));                        // padded x16
    float* ea_loop = (float*)(ws + alloc((size_t)n * 4));
    int*   bsum    = (int*)  (ws + alloc(64 * 4));
    int2*  spk     = (int2*) (ws + alloc((size_t)E * 8));
    unsigned short* xb   = (unsigned short*)(ws + alloc((size_t)n * F * 2));
    unsigned short* Wt1  = (unsigned short*)(ws + alloc((size_t)F * (2 * HC1) * 2));
    unsigned short* Wt2  = (unsigned short*)(ws + alloc((size_t)HC1 * (2 * HC2) * 2));
    float* b1cat   = (float*)(ws + alloc((size_t)2 * HC1 * 4));
    float* b2cat   = (float*)(ws + alloc((size_t)2 * HC2 * 4));
    unsigned char* xlr1 = (unsigned char*)(ws + alloc((size_t)n * 2 * HC1));   // fp8
    unsigned short* h1  = (unsigned short*)(ws + alloc((size_t)n * HC1 * 2));  // bf16
    float* partial = (float*)(ws + alloc((size_t)256 * 128 * 4));
    unsigned char* xlr2 = xlr1;   // layer-2 fp8 projections alias layer-1 buffer
    const int NB_SLOTS = 256;

    (void)hipMemsetAsync(hist, 0, (size_t)n * 8 * 8, stream);
    (void)hipMemsetAsync(partial, 0, (size_t)NB_SLOTS * 128 * 4, stream);

    int tb = 256;
    {
        int nF4  = n * F / 4;
        int WTOT = 2 * F * HC1 + 2 * HC1 * HC2 + 2 * HC1 + 2 * HC2;
        int total = E + nF4 + WTOT;
        fused_prep<<<(total + tb - 1) / tb, tb, 0, stream>>>(
            ei, ea, hist, E, x, xb, nF4,
            W1l, W1r, W2l, W2r, b1l, b1r, b2l, b2r,
            Wt1, Wt2, b1cat, b2cat, F, HC1, HC2);
    }
    scan_a<<<B, 256, 0, stream>>>(hist, bsum, n);
    scan_c<<<B, 256, 0, stream>>>(hist, bsum, row_ptr, wptr, ea_loop, n, B);
    edge_scatter<<<(E + tb - 1) / tb, tb, 0, stream>>>(ei, ea, wptr, spk, E);

    // layer 1: merged GEMM [n,128]@[128,512] -> xlr1 (fp8, xl|xr rows)
    {
        dim3 grid((n + 63) / 64, (2 * HC1) / 64);
        gemm_bf16<true><<<grid, 256, 0, stream>>>(xb, Wt1, b1cat, xlr1, n, 2 * HC1, F);
    }
    gat_agg<256, 512, 32, 0><<<(n + 3) / 4, 256, 0, stream>>>(
        xlr1, We1, att1, bias1, row_ptr, spk, ea_loop, h1, n);

    // layer 2: merged GEMM [n,256]@[256,256] -> xlr2 (fp8)
    {
        dim3 grid((n + 63) / 64, (2 * HC2) / 64);
        gemm_bf16<true><<<grid, 256, 0, stream>>>(h1, Wt2, b2cat, xlr2, n, 2 * HC2, HC1);
    }
    // layer-2 gat with fused pooling (writes partial, skips h2)
    gat_agg<128, 256, 128, 1><<<(n + 3) / 4, 256, 0, stream>>>(
        xlr2, We2, att2, bias2, row_ptr, spk, ea_loop, partial, n);

    pool_final<<<1, 1024, 0, stream>>>(partial, NB_SLOTS, alpha, out, n);
}

// Round 2
// 284.090 us; speedup vs baseline: 1.0286x; 1.0286x over previous
//
#include <hip/hip_runtime.h>
#include <math.h>

#define NEG_SLOPE 0.2f
#define LOG2E 1.4426950408889634f

typedef __attribute__((ext_vector_type(8))) short short8;   // 8 bf16 (4 VGPRs)
typedef __attribute__((ext_vector_type(4))) float f32x4;
typedef __attribute__((ext_vector_type(2))) float v2f;

__device__ __forceinline__ int imin(int a, int b) { return a < b ? a : b; }

__device__ __forceinline__ unsigned int f2bf(float f) {
    unsigned int u = __float_as_uint(f);
    return (u + 0x7fffu + ((u >> 16) & 1u)) >> 16;   // RNE
}
__device__ __forceinline__ float fast_exp2(float x) {
#if __has_builtin(__builtin_amdgcn_exp2f)
    return __builtin_amdgcn_exp2f(x);
#else
    return exp2f(x);
#endif
}
// fp8 (OCP e4m3 on gfx950) hardware pack/unpack
__device__ __forceinline__ unsigned char f2fp8(float v) {
    return (unsigned char)(__builtin_amdgcn_cvt_pk_fp8_f32(v, v, 0, false) & 0xff);
}
template <int CTRL>
__device__ __forceinline__ float dpp_add(float v) {
    int t = __builtin_amdgcn_update_dpp(0, __float_as_int(v), CTRL, 0xF, 0xF, true);
    return v + __int_as_float(t);
}
// gfx90a+ packed-FP32 VALU (2 channels / instruction) — hipcc scalarizes
// float2 arithmetic, so force the pk forms via asm.
__device__ __forceinline__ v2f pk_fma(v2f a, v2f b, v2f c) {
    v2f d;
    asm("v_pk_fma_f32 %0, %1, %2, %3" : "=v"(d) : "v"(a), "v"(b), "v"(c));
    return d;
}
__device__ __forceinline__ v2f pk_add(v2f a, v2f b) {
    v2f d;
    asm("v_pk_add_f32 %0, %1, %2" : "=v"(d) : "v"(a), "v"(b));
    return d;
}

// ---------------------------------------------------------------------------
// Fused prep kernel: three disjoint index ranges in one launch.
//  [0, E)            : packed histogram (64-bit atomic, 64B-padded slots)
//  [E, E+nF4)        : x fp32 -> bf16 (vec4)
//  [E+nF4, ..+WTOT)  : weight transposes -> bf16 + bias concats
// ---------------------------------------------------------------------------
__global__ void fused_prep(const int* __restrict__ ei, const float* __restrict__ ea,
                           unsigned long long* __restrict__ hist, int E,
                           const float* __restrict__ x, unsigned short* __restrict__ xb, int nF4,
                           const float* __restrict__ W1l, const float* __restrict__ W1r,
                           const float* __restrict__ W2l, const float* __restrict__ W2r,
                           const float* __restrict__ b1l, const float* __restrict__ b1r,
                           const float* __restrict__ b2l, const float* __restrict__ b2r,
                           unsigned short* __restrict__ Wt1, unsigned short* __restrict__ Wt2,
                           float* __restrict__ b1cat, float* __restrict__ b2cat,
                           int F, int HC1, int HC2) {
    int i = blockIdx.x * blockDim.x + threadIdx.x;
    if (i < E) {
        int d = ei[E + i];
        long long fx = (long long)__float2int_rn(ea[i] * 65536.0f);
        unsigned long long v = ((unsigned long long)fx << 32) | 1ull;
        atomicAdd(&hist[(size_t)d * 8], v);
        return;
    }
    int j = i - E;
    if (j < nF4) {
        float4 v = ((const float4*)x)[j];
        uint2 r;
        r.x = f2bf(v.x) | (f2bf(v.y) << 16);
        r.y = f2bf(v.z) | (f2bf(v.w) << 16);
        ((uint2*)xb)[j] = r;
        return;
    }
    int k = j - nF4;
    int S1 = F * HC1, S2 = HC1 * HC2;
    if (k < S1) {
        int kk = k / HC1, nn = k - kk * HC1;
        Wt1[(size_t)nn * F + kk] = (unsigned short)f2bf(W1l[k]);
    } else if (k < 2 * S1) {
        int m = k - S1;
        int kk = m / HC1, nn = m - kk * HC1;
        Wt1[(size_t)(HC1 + nn) * F + kk] = (unsigned short)f2bf(W1r[m]);
    } else if (k < 2 * S1 + S2) {
        int m = k - 2 * S1;
        int kk = m / HC2, nn = m - kk * HC2;
        Wt2[(size_t)nn * HC1 + kk] = (unsigned short)f2bf(W2l[m]);
    } else if (k < 2 * S1 + 2 * S2) {
        int m = k - 2 * S1 - S2;
        int kk = m / HC2, nn = m - kk * HC2;
        Wt2[(size_t)(HC2 + nn) * HC1 + kk] = (unsigned short)f2bf(W2r[m]);
    } else if (k < 2 * S1 + 2 * S2 + 2 * HC1) {
        int m = k - 2 * S1 - 2 * S2;
        b1cat[m] = (m < HC1) ? b1l[m] : b1r[m - HC1];
    } else if (k < 2 * S1 + 2 * S2 + 2 * HC1 + 2 * HC2) {
        int m = k - 2 * S1 - 2 * S2 - 2 * HC1;
        b2cat[m] = (m < HC2) ? b2l[m] : b2r[m - HC2];
    }
}

// ---------------------------------------------------------------------------
// 2-phase parallel scan over hist (padded stride 8): scan_a computes raw
// block sums; scan_c derives its own prefix from bsum in-wave (scan_b folded).
// ---------------------------------------------------------------------------
__global__ void scan_a(const unsigned long long* __restrict__ hist, int* __restrict__ bsum, int n) {
    __shared__ int wred[4];
    int base = blockIdx.x * 1024;
    int tid = threadIdx.x;
    int s = 0;
#pragma unroll
    for (int k = 0; k < 4; ++k) {
        int i = base + tid + k * 256;
        if (i < n) s += (int)(hist[(size_t)i * 8] & 0xffffffffull);
    }
#pragma unroll
    for (int off = 32; off > 0; off >>= 1) s += __shfl_xor(s, off, 64);
    if ((tid & 63) == 0) wred[tid >> 6] = s;
    __syncthreads();
    if (tid == 0) bsum[blockIdx.x] = wred[0] + wred[1] + wred[2] + wred[3];
}

__global__ void scan_c(const unsigned long long* __restrict__ hist,
                       const int* __restrict__ bsum, int* __restrict__ row_ptr,
                       int* __restrict__ wptr_pad, float* __restrict__ ea_loop,
                       int n, int B) {
    __shared__ int wtot[4];
    __shared__ int sh_base;
    int tid = threadIdx.x;
    int wid = tid >> 6, lane = tid & 63;
    int i0 = blockIdx.x * 1024 + tid * 4;
    int dcnt[4]; float esum[4];
#pragma unroll
    for (int k = 0; k < 4; ++k) {
        if (i0 + k < n) {
            unsigned long long h = hist[(size_t)(i0 + k) * 8];
            dcnt[k] = (int)(h & 0xffffffffull);
            esum[k] = (float)((int)(h >> 32)) * (1.0f / 65536.0f);
        } else { dcnt[k] = 0; esum[k] = 0.0f; }
    }
    int tsum = dcnt[0] + dcnt[1] + dcnt[2] + dcnt[3];
    int s = tsum;
#pragma unroll
    for (int off = 1; off < 64; off <<= 1) {
        int t = __shfl_up(s, off, 64);
        if (lane >= off) s += t;
    }
    if (lane == 63) wtot[wid] = s;
    // wave 0: block prefix (sum of bsum[0..blockIdx)) and grand total
    if (tid < 64) {
        int v   = (tid < B) ? bsum[tid] : 0;
        int pre = (tid < (int)blockIdx.x) ? v : 0;
        int tot = v;
#pragma unroll
        for (int off = 32; off > 0; off >>= 1) {
            pre += __shfl_xor(pre, off, 64);
            tot += __shfl_xor(tot, off, 64);
        }
        if (tid == 0) {
            sh_base = pre;
            if (blockIdx.x == 0) row_ptr[n] = tot;
        }
    }
    __syncthreads();
    int wpre = 0;
#pragma unroll
    for (int k = 0; k < 4; ++k) if (k < wid) wpre += wtot[k];
    int pre = sh_base + wpre + (s - tsum);
    if (i0 < n) {
        int4 e;
        e.x = pre;
        e.y = pre + dcnt[0];
        e.z = e.y + dcnt[1];
        e.w = e.z + dcnt[2];
        *(int4*)(row_ptr + i0) = e;
        int ev[4] = { e.x, e.y, e.z, e.w };
        float4 el;
        el.x = esum[0] / fmaxf((float)dcnt[0], 1.0f);
        el.y = esum[1] / fmaxf((float)dcnt[1], 1.0f);
        el.z = esum[2] / fmaxf((float)dcnt[2], 1.0f);
        el.w = esum[3] / fmaxf((float)dcnt[3], 1.0f);
        *(float4*)(ea_loop + i0) = el;
#pragma unroll
        for (int k = 0; k < 4; ++k) wptr_pad[(size_t)(i0 + k) * 16] = ev[k];
    }
}

// ---------------------------------------------------------------------------
// scatter edges into CSR order; (src,w) packed as int2.
// ---------------------------------------------------------------------------
__global__ void edge_scatter(const int* __restrict__ ei, const float* __restrict__ ea,
                             int* __restrict__ wptr_pad, int2* __restrict__ spk, int E) {
    int e = blockIdx.x * blockDim.x + threadIdx.x;
    if (e < E) {
        int d = ei[E + e];
        int pos = atomicAdd(&wptr_pad[(size_t)d * 16], 1);
        spk[pos] = make_int2(ei[e], __float_as_int(ea[e]));
    }
}

// ---------------------------------------------------------------------------
// bf16 MFMA GEMM + bias (B pre-transposed), 64x64 tile, BK=32.
// OUT_FP8: epilogue packs to fp8 (e4m3, hardware RNE) else bf16.
// ---------------------------------------------------------------------------
template <bool OUT_FP8>
__global__ void __launch_bounds__(256)
gemm_bf16(const unsigned short* __restrict__ A, const unsigned short* __restrict__ Bt,
          const float* __restrict__ bias, void* __restrict__ Cv,
          int M, int N, int K) {
    __shared__ __attribute__((aligned(16))) unsigned short As[64 * 40];
    __shared__ __attribute__((aligned(16))) unsigned short Bs[64 * 40];
    int tid  = threadIdx.x;
    int wave = tid >> 6, lane = tid & 63;
    int m0 = blockIdx.x * 64, n0 = blockIdx.y * 64;
    int row = tid >> 2, kg = (tid & 3) * 8;

    f32x4 acc[4] = {};
    for (int kk = 0; kk < K; kk += 32) {
        int gm = m0 + row;
        uint4 av;
        if (gm < M) av = *(const uint4*)(A + (size_t)gm * K + kk + kg);
        else        av = make_uint4(0, 0, 0, 0);
        *(uint4*)&As[row * 40 + kg] = av;
        uint4 bv = *(const uint4*)(Bt + (size_t)(n0 + row) * K + kk + kg);
        *(uint4*)&Bs[row * 40 + kg] = bv;
        __syncthreads();
        short8 a = *(const short8*)&As[(wave * 16 + (lane & 15)) * 40 + (lane >> 4) * 8];
#pragma unroll
        for (int g = 0; g < 4; ++g) {
            short8 b = *(const short8*)&Bs[(g * 16 + (lane & 15)) * 40 + (lane >> 4) * 8];
            acc[g] = __builtin_amdgcn_mfma_f32_16x16x32_bf16(a, b, acc[g], 0, 0, 0);
        }
        __syncthreads();
    }
#pragma unroll
    for (int g = 0; g < 4; ++g) {
        int col = n0 + g * 16 + (lane & 15);
        float bs = bias[col];
#pragma unroll
        for (int r = 0; r < 4; ++r) {
            int grow = m0 + wave * 16 + (lane >> 4) * 4 + r;
            if (grow < M) {
                float val = acc[g][r] + bs;
                if constexpr (OUT_FP8) {
                    ((unsigned char*)Cv)[(size_t)grow * N + col] = f2fp8(val);
                } else {
                    ((unsigned short*)Cv)[(size_t)grow * N + col] = (unsigned short)f2bf(val);
                }
            }
        }
    }
}

// ---------------------------------------------------------------------------
// helpers for gat_agg (fp8 gather, packed-f32 math)
// ---------------------------------------------------------------------------
template <int NG>
__device__ __forceinline__ void unp2(uint2 u, v2f* xf) {
    xf[0] = __builtin_amdgcn_cvt_pk_f32_fp8(u.x, false);
    xf[1] = __builtin_amdgcn_cvt_pk_f32_fp8(u.x, true);
    if constexpr (NG == 4) {
        xf[2] = __builtin_amdgcn_cvt_pk_f32_fp8(u.y, false);
        xf[3] = __builtin_amdgcn_cvt_pk_f32_fp8(u.y, true);
    }
}
// reduction over G lanes, confined within each 32-lane half-wave
template <int G>
__device__ __forceinline__ float grp_reduce32(float vs) {
    vs = dpp_add<0xB1>(vs);                               // xor 1
    if constexpr (G >= 4)  vs = dpp_add<0x4E>(vs);        // xor 2
    if constexpr (G >= 8)  vs = dpp_add<0x141>(vs);       // xor 4 (row_half_mirror)
    if constexpr (G >= 16) vs = dpp_add<0x140>(vs);       // xor 8 (row_mirror)
    if constexpr (G >= 32) {                              // xor 16 (within 32-group)
        int t = __builtin_amdgcn_ds_swizzle(__float_as_int(vs), 0x401F);
        vs += __int_as_float(t);
    }
    return vs;
}

// ---------------------------------------------------------------------------
// fused GATv2 gather(fp8) + score + softmax + aggregate + relu.
// TWO EDGES PER WAVE: lanes 0-31 process edge A, lanes 32-63 edge B; each lane
// covers NV = HC/32 channels.  Channel math forced to v_pk_fma_f32 /
// v_pk_add_f32 (asm; hipcc scalarizes float2).  leaky-relu as two
// accumulators: vs6 = sum att6*mm (packed) and vs4 = sum att6*|mm| (scalar
// fma, free abs modifier), combined as vs6 + (2/3)*vs4 since att4=(2/3)att6.
// (src,w) comes from a uniform per-half global load (spk[start+2p+half]) —
// no readlane/cndmask broadcast.  3-stage pipeline: sw prefetched 2 pairs
// ahead, gather 1 process ahead.  spk is zero-padded by 8 entries so
// prefetch overshoot gathers row 0 harmlessly (never processed).
// OUT_MODE 0: dense bf16 rows.  OUT_MODE 1: fused pooling into partial slots.
// ---------------------------------------------------------------------------
template <int HC, int STRIDE, int C, int OUT_MODE>
__global__ void __launch_bounds__(256)
gat_agg(const unsigned char* __restrict__ xlr,
        const float* __restrict__ We, const float* __restrict__ att,
        const float* __restrict__ bias,
        const int* __restrict__ row_ptr, const int2* __restrict__ spk,
        const float* __restrict__ ea_loop,
        void* __restrict__ out, int n) {
    constexpr int NV = HC / 32;      // channels (bytes) per lane
    constexpr int NG = NV / 2;       // float2 groups per lane
    constexpr int G  = C / NV;       // lanes per head within a half-wave
    constexpr int SHIFT = (STRIDE == 512) ? 9 : 8;
    constexpr float K23 = 2.0f / 3.0f;
    int wave = threadIdx.x >> 6;
    int lane = threadIdx.x & 63;
    int node = blockIdx.x * 4 + wave;
    if (node >= n) return;
    unsigned int lo32 = (unsigned int)(lane & 31) * NV;   // channel/byte offset
    int half = lane >> 5;

    auto ldd = [&](unsigned int off) -> uint2 {
        uint2 r;
        if constexpr (NV == 8) r = *(const uint2*)(xlr + off);
        else { r.x = *(const unsigned int*)(xlr + off); r.y = 0u; }
        return r;
    };
    auto gat = [&](int s) -> uint2 {
        return ldd(((unsigned int)s << SHIFT) + lo32);
    };

    v2f xr2[NG], We2[NG], att62[NG], o2[NG];
    unp2<NG>(ldd(((unsigned int)node << SHIFT) + HC + lo32), xr2);
#pragma unroll
    for (int g = 0; g < NG; ++g) {
        We2[g]   = *(const v2f*)(We  + lo32 + 2 * g);
        v2f a    = *(const v2f*)(att + lo32 + 2 * g);
        att62[g] = a * (0.6f * LOG2E);
        o2[g]    = v2f{0.0f, 0.0f};
    }
    float l = 0.0f;

    int start = __builtin_amdgcn_readfirstlane(row_ptr[node]);
    int end   = __builtin_amdgcn_readfirstlane(row_ptr[node + 1]);
    float ea_l = ea_loop[node];

    auto process = [&](uint2 du, float w, bool maskhi) {
        v2f xf[NG];
        unp2<NG>(du, xf);
        v2f w2 = {w, w};
        v2f vs6 = {0.0f, 0.0f};
        float vs4 = 0.0f;
#pragma unroll
        for (int g = 0; g < NG; ++g) {
            v2f t  = pk_fma(w2, We2[g], xr2[g]);     // xr + w*We
            v2f mm = pk_add(xf[g], t);               // xl[src] + xr + w*We
            vs6 = pk_fma(att62[g], mm, vs6);
            vs4 = fmaf(fabsf(mm.x), att62[g].x, vs4);   // abs = free modifier
            vs4 = fmaf(fabsf(mm.y), att62[g].y, vs4);
        }
        float vs = fmaf(K23, vs4, vs6.x + vs6.y);
        vs = grp_reduce32<G>(vs);
        float pr = fast_exp2(vs);
        if (maskhi && lane >= 32) pr = 0.0f;
        l += pr;
        v2f pr2 = {pr, pr};
#pragma unroll
        for (int g = 0; g < NG; ++g) o2[g] = pk_fma(xf[g], pr2, o2[g]);
    };

    // ---- self-loop edge (both halves compute same edge; upper half masked) ----
    process(ldd(((unsigned int)node << SHIFT) + lo32), ea_l, true);

    // ---- real edges: pairs across half-waves, direct uniform sw loads ----
    int cnt = end - start;
    int npair = cnt >> 1;
    const int2* pp = spk + start + half;   // this half's edge stream (stride 2 pairs)

    if (npair >= 2) {
        int2 sA = pp[0], sB = pp[2];
        uint2 gA = gat(sA.x);
        int p = 0;
        for (; p + 2 < npair; p += 2) {
            uint2 gB = gat(sB.x);
            int2 sC = pp[2 * p + 4];
            process(gA, __int_as_float(sA.y), false);
            uint2 gC = gat(sC.x);
            int2 sD = pp[2 * p + 6];
            process(gB, __int_as_float(sB.y), false);
            sA = sC; sB = sD; gA = gC;
        }
        // 1 or 2 pairs remain: sA = pair p, sB = pair p+1 (maybe OOB-prefetched)
        if (npair - p == 2) {
            uint2 gB = gat(sB.x);
            process(gA, __int_as_float(sA.y), false);
            process(gB, __int_as_float(sB.y), false);
        } else {
            process(gA, __int_as_float(sA.y), false);
        }
    } else if (npair == 1) {
        int2 sA = pp[0];
        process(gat(sA.x), __int_as_float(sA.y), false);
    }
    if (cnt & 1) {   // odd tail edge: both halves same edge, upper masked
        int2 st = spk[end - 1];
        process(gat(st.x), __int_as_float(st.y), true);
    }

    // ---- combine the two half-wave accumulators (all lanes active) ----
    l += __shfl_xor(l, 32, 64);
#pragma unroll
    for (int g = 0; g < NG; ++g) {
        o2[g].x += __shfl_xor(o2[g].x, 32, 64);
        o2[g].y += __shfl_xor(o2[g].y, 32, 64);
    }
    float inv = 1.0f / (l + 1e-16f);

    if (lane < 32) {
        float v[NV];
#pragma unroll
        for (int g = 0; g < NG; ++g) {
            v2f b = *(const v2f*)(bias + lo32 + 2 * g);
            v[2 * g]     = fmaxf(o2[g].x * inv + b.x, 0.0f);
            v[2 * g + 1] = fmaxf(o2[g].y * inv + b.y, 0.0f);
        }
        if constexpr (OUT_MODE == 0) {
            // dense bf16 rows (h1)
            unsigned short* op = (unsigned short*)out + (size_t)node * HC + lo32;
            if constexpr (NV == 8) {
                uint4 t;
                t.x = f2bf(v[0]) | (f2bf(v[1]) << 16);
                t.y = f2bf(v[2]) | (f2bf(v[3]) << 16);
                t.z = f2bf(v[4]) | (f2bf(v[5]) << 16);
                t.w = f2bf(v[6]) | (f2bf(v[7]) << 16);
                *(uint4*)op = t;
            } else {
                uint2 t;
                t.x = f2bf(v[0]) | (f2bf(v[1]) << 16);
                t.y = f2bf(v[2]) | (f2bf(v[3]) << 16);
                *(uint2*)op = t;
            }
        } else {
            // fused pooling: accumulate relu'd row into partial slot
            float* pacc = (float*)out + (size_t)(blockIdx.x & 255) * 128 + lo32;
#pragma unroll
            for (int j = 0; j < NV; ++j) atomicAdd(&pacc[j], v[j]);
        }
    }
}

// ---------------------------------------------------------------------------
// finish pooling, softmax over 128, sigmoid(alpha). 1024 threads.
// ---------------------------------------------------------------------------
__global__ void __launch_bounds__(1024)
pool_final(const float* __restrict__ partial, int nb,
           const float* __restrict__ alpha_in,
           float* __restrict__ out, int n) {
    __shared__ float acc[8][128];
    __shared__ float red[4];
    int t = threadIdx.x & 127;        // column
    int g = threadIdx.x >> 7;         // group 0..7
    float s = 0.0f;
    for (int b = g; b < nb; b += 8) s += partial[b * 128 + t];
    acc[g][t] = s;
    __syncthreads();
    if (threadIdx.x < 128) {
        float tot = 0.0f;
#pragma unroll
        for (int k = 0; k < 8; ++k) tot += acc[k][t];
        float mean = tot / (float)n;
        float mx = mean;
#pragma unroll
        for (int off = 32; off > 0; off >>= 1) mx = fmaxf(mx, __shfl_xor(mx, off, 64));
        if ((t & 63) == 0) red[t >> 6] = mx;
        __syncthreads();
        mx = fmaxf(red[0], red[1]);
        float ex = __expf(mean - mx);
        float sm = ex;
#pragma unroll
        for (int off = 32; off > 0; off >>= 1) sm += __shfl_xor(sm, off, 64);
        if ((t & 63) == 0) red[2 + (t >> 6)] = sm;
        __syncthreads();
        sm = red[2] + red[3];
        out[t] = ex / sm;
        if (t == 0) out[128] = 1.0f / (1.0f + __expf(-alpha_in[0]));
    }
}

// ---------------------------------------------------------------------------
extern "C" void kernel_launch(void* const* d_in, const int* in_sizes, int n_in,
                              void* d_out, int out_size, void* d_ws, size_t ws_size,
                              hipStream_t stream) {
    const float* x    = (const float*)d_in[0];
    const int*   ei   = (const int*)d_in[1];
    const float* ea   = (const float*)d_in[2];
    const float* W1l  = (const float*)d_in[3];
    const float* b1l  = (const float*)d_in[4];
    const float* W1r  = (const float*)d_in[5];
    const float* b1r  = (const float*)d_in[6];
    const float* We1  = (const float*)d_in[7];
    const float* att1 = (const float*)d_in[8];
    const float* bias1= (const float*)d_in[9];
    const float* W2l  = (const float*)d_in[10];
    const float* b2l  = (const float*)d_in[11];
    const float* W2r  = (const float*)d_in[12];
    const float* b2r  = (const float*)d_in[13];
    const float* We2  = (const float*)d_in[14];
    const float* att2 = (const float*)d_in[15];
    const float* bias2= (const float*)d_in[16];
    const float* alpha= (const float*)d_in[17];
    float* out = (float*)d_out;

    const int F = 128, HC1 = 256, HC2 = 128;
    const int n = in_sizes[0] / F;       // 20000
    const int E = in_sizes[1] / 2;       // 640000
    const int B = (n + 1023) / 1024;     // scan blocks

    char* ws = (char*)d_ws;
    size_t off = 0;
    auto alloc = [&](size_t bytes) { size_t p = off; off += (bytes + 255) & ~(size_t)255; return p; };

    unsigned long long* hist = (unsigned long long*)(ws + alloc((size_t)n * 8 * 8));  // padded x8
    int*   row_ptr = (int*)  (ws + alloc((size_t)(n + 1) * 4));
    int*   wptr    = (int*)  (ws + alloc((size_t)n * 16 * 4));                        // padded x16
    float* ea_loop = (float*)(ws + alloc((size_t)n * 4));
    int*   bsum    = (int*)  (ws + alloc(64 * 4));
    int2*  spk     = (int2*) (ws + alloc((size_t)(E + 8) * 8));                       // +8 zero pad
    unsigned short* xb   = (unsigned short*)(ws + alloc((size_t)n * F * 2));
    unsigned short* Wt1  = (unsigned short*)(ws + alloc((size_t)F * (2 * HC1) * 2));
    unsigned short* Wt2  = (unsigned short*)(ws + alloc((size_t)HC1 * (2 * HC2) * 2));
    float* b1cat   = (float*)(ws + alloc((size_t)2 * HC1 * 4));
    float* b2cat   = (float*)(ws + alloc((size_t)2 * HC2 * 4));
    unsigned char* xlr1 = (unsigned char*)(ws + alloc((size_t)n * 2 * HC1));   // fp8
    unsigned short* h1  = (unsigned short*)(ws + alloc((size_t)n * HC1 * 2));  // bf16
    float* partial = (float*)(ws + alloc((size_t)256 * 128 * 4));
    unsigned char* xlr2 = xlr1;   // layer-2 fp8 projections alias layer-1 buffer
    const int NB_SLOTS = 256;

    (void)hipMemsetAsync(hist, 0, (size_t)n * 8 * 8, stream);
    (void)hipMemsetAsync(partial, 0, (size_t)NB_SLOTS * 128 * 4, stream);
    (void)hipMemsetAsync(spk + E, 0, 8 * sizeof(int2), stream);   // safe prefetch pad

    int tb = 256;
    {
        int nF4  = n * F / 4;
        int WTOT = 2 * F * HC1 + 2 * HC1 * HC2 + 2 * HC1 + 2 * HC2;
        int total = E + nF4 + WTOT;
        fused_prep<<<(total + tb - 1) / tb, tb, 0, stream>>>(
            ei, ea, hist, E, x, xb, nF4,
            W1l, W1r, W2l, W2r, b1l, b1r, b2l, b2r,
            Wt1, Wt2, b1cat, b2cat, F, HC1, HC2);
    }
    scan_a<<<B, 256, 0, stream>>>(hist, bsum, n);
    scan_c<<<B, 256, 0, stream>>>(hist, bsum, row_ptr, wptr, ea_loop, n, B);
    edge_scatter<<<(E + tb - 1) / tb, tb, 0, stream>>>(ei, ea, wptr, spk, E);

    // layer 1: merged GEMM [n,128]@[128,512] -> xlr1 (fp8, xl|xr rows)
    {
        dim3 grid((n + 63) / 64, (2 * HC1) / 64);
        gemm_bf16<true><<<grid, 256, 0, stream>>>(xb, Wt1, b1cat, xlr1, n, 2 * HC1, F);
    }
    gat_agg<256, 512, 32, 0><<<(n + 3) / 4, 256, 0, stream>>>(
        xlr1, We1, att1, bias1, row_ptr, spk, ea_loop, h1, n);

    // layer 2: merged GEMM [n,256]@[256,256] -> xlr2 (fp8)
    {
        dim3 grid((n + 63) / 64, (2 * HC2) / 64);
        gemm_bf16<true><<<grid, 256, 0, stream>>>(h1, Wt2, b2cat, xlr2, n, 2 * HC2, HC1);
    }
    // layer-2 gat with fused pooling (writes partial, skips h2)
    gat_agg<128, 256, 128, 1><<<(n + 3) / 4, 256, 0, stream>>>(
        xlr2, We2, att2, bias2, row_ptr, spk, ea_loop, partial, n);

    pool_final<<<1, 1024, 0, stream>>>(partial, NB_SLOTS, alpha, out, n);
}

// Round 4
// 279.147 us; speedup vs baseline: 1.0468x; 1.0177x over previous
//
#include <hip/hip_runtime.h>
#include <math.h>

#define NEG_SLOPE 0.2f
#define LOG2E 1.4426950408889634f

typedef __attribute__((ext_vector_type(8))) short short8;   // 8 bf16 (4 VGPRs)
typedef __attribute__((ext_vector_type(4))) float f32x4;
typedef __attribute__((ext_vector_type(2))) float v2f;

__device__ __forceinline__ int imin(int a, int b) { return a < b ? a : b; }

__device__ __forceinline__ unsigned int f2bf(float f) {
    unsigned int u = __float_as_uint(f);
    return (u + 0x7fffu + ((u >> 16) & 1u)) >> 16;   // RNE
}
__device__ __forceinline__ float fast_exp2(float x) {
#if __has_builtin(__builtin_amdgcn_exp2f)
    return __builtin_amdgcn_exp2f(x);
#else
    return exp2f(x);
#endif
}
// fp8 (OCP e4m3 on gfx950) hardware pack/unpack
__device__ __forceinline__ unsigned char f2fp8(float v) {
    return (unsigned char)(__builtin_amdgcn_cvt_pk_fp8_f32(v, v, 0, false) & 0xff);
}
template <int CTRL>
__device__ __forceinline__ float dpp_add(float v) {
    int t = __builtin_amdgcn_update_dpp(0, __float_as_int(v), CTRL, 0xF, 0xF, true);
    return v + __int_as_float(t);
}
// gfx90a+ packed-FP32 VALU (2 channels / instruction) — hipcc scalarizes
// float2 arithmetic, so force the pk forms via asm.
__device__ __forceinline__ v2f pk_fma(v2f a, v2f b, v2f c) {
    v2f d;
    asm("v_pk_fma_f32 %0, %1, %2, %3" : "=v"(d) : "v"(a), "v"(b), "v"(c));
    return d;
}
__device__ __forceinline__ v2f pk_add(v2f a, v2f b) {
    v2f d;
    asm("v_pk_add_f32 %0, %1, %2" : "=v"(d) : "v"(a), "v"(b));
    return d;
}

// ---------------------------------------------------------------------------
// Fused prep kernel: three disjoint index ranges in one launch.
//  [0, E)            : packed histogram (64-bit atomic, 64B-padded slots)
//  [E, E+nF4)        : x fp32 -> bf16 (vec4)
//  [E+nF4, ..+WTOT)  : weight transposes -> bf16 + bias concats
// ---------------------------------------------------------------------------
__global__ void fused_prep(const int* __restrict__ ei, const float* __restrict__ ea,
                           unsigned long long* __restrict__ hist, int E,
                           const float* __restrict__ x, unsigned short* __restrict__ xb, int nF4,
                           const float* __restrict__ W1l, const float* __restrict__ W1r,
                           const float* __restrict__ W2l, const float* __restrict__ W2r,
                           const float* __restrict__ b1l, const float* __restrict__ b1r,
                           const float* __restrict__ b2l, const float* __restrict__ b2r,
                           unsigned short* __restrict__ Wt1, unsigned short* __restrict__ Wt2,
                           float* __restrict__ b1cat, float* __restrict__ b2cat,
                           int F, int HC1, int HC2) {
    int i = blockIdx.x * blockDim.x + threadIdx.x;
    if (i < E) {
        int d = ei[E + i];
        long long fx = (long long)__float2int_rn(ea[i] * 65536.0f);
        unsigned long long v = ((unsigned long long)fx << 32) | 1ull;
        atomicAdd(&hist[(size_t)d * 8], v);
        return;
    }
    int j = i - E;
    if (j < nF4) {
        float4 v = ((const float4*)x)[j];
        uint2 r;
        r.x = f2bf(v.x) | (f2bf(v.y) << 16);
        r.y = f2bf(v.z) | (f2bf(v.w) << 16);
        ((uint2*)xb)[j] = r;
        return;
    }
    int k = j - nF4;
    int S1 = F * HC1, S2 = HC1 * HC2;
    if (k < S1) {
        int kk = k / HC1, nn = k - kk * HC1;
        Wt1[(size_t)nn * F + kk] = (unsigned short)f2bf(W1l[k]);
    } else if (k < 2 * S1) {
        int m = k - S1;
        int kk = m / HC1, nn = m - kk * HC1;
        Wt1[(size_t)(HC1 + nn) * F + kk] = (unsigned short)f2bf(W1r[m]);
    } else if (k < 2 * S1 + S2) {
        int m = k - 2 * S1;
        int kk = m / HC2, nn = m - kk * HC2;
        Wt2[(size_t)nn * HC1 + kk] = (unsigned short)f2bf(W2l[m]);
    } else if (k < 2 * S1 + 2 * S2) {
        int m = k - 2 * S1 - S2;
        int kk = m / HC2, nn = m - kk * HC2;
        Wt2[(size_t)(HC2 + nn) * HC1 + kk] = (unsigned short)f2bf(W2r[m]);
    } else if (k < 2 * S1 + 2 * S2 + 2 * HC1) {
        int m = k - 2 * S1 - 2 * S2;
        b1cat[m] = (m < HC1) ? b1l[m] : b1r[m - HC1];
    } else if (k < 2 * S1 + 2 * S2 + 2 * HC1 + 2 * HC2) {
        int m = k - 2 * S1 - 2 * S2 - 2 * HC1;
        b2cat[m] = (m < HC2) ? b2l[m] : b2r[m - HC2];
    }
}

// ---------------------------------------------------------------------------
// 2-phase parallel scan over hist (padded stride 8): scan_a computes raw
// block sums; scan_c derives its own prefix from bsum in-wave (scan_b folded).
// ---------------------------------------------------------------------------
__global__ void scan_a(const unsigned long long* __restrict__ hist, int* __restrict__ bsum, int n) {
    __shared__ int wred[4];
    int base = blockIdx.x * 1024;
    int tid = threadIdx.x;
    int s = 0;
#pragma unroll
    for (int k = 0; k < 4; ++k) {
        int i = base + tid + k * 256;
        if (i < n) s += (int)(hist[(size_t)i * 8] & 0xffffffffull);
    }
#pragma unroll
    for (int off = 32; off > 0; off >>= 1) s += __shfl_xor(s, off, 64);
    if ((tid & 63) == 0) wred[tid >> 6] = s;
    __syncthreads();
    if (tid == 0) bsum[blockIdx.x] = wred[0] + wred[1] + wred[2] + wred[3];
}

__global__ void scan_c(const unsigned long long* __restrict__ hist,
                       const int* __restrict__ bsum, int* __restrict__ row_ptr,
                       int* __restrict__ wptr_pad, float* __restrict__ ea_loop,
                       int n, int B) {
    __shared__ int wtot[4];
    __shared__ int sh_base;
    int tid = threadIdx.x;
    int wid = tid >> 6, lane = tid & 63;
    int i0 = blockIdx.x * 1024 + tid * 4;
    int dcnt[4]; float esum[4];
#pragma unroll
    for (int k = 0; k < 4; ++k) {
        if (i0 + k < n) {
            unsigned long long h = hist[(size_t)(i0 + k) * 8];
            dcnt[k] = (int)(h & 0xffffffffull);
            esum[k] = (float)((int)(h >> 32)) * (1.0f / 65536.0f);
        } else { dcnt[k] = 0; esum[k] = 0.0f; }
    }
    int tsum = dcnt[0] + dcnt[1] + dcnt[2] + dcnt[3];
    int s = tsum;
#pragma unroll
    for (int off = 1; off < 64; off <<= 1) {
        int t = __shfl_up(s, off, 64);
        if (lane >= off) s += t;
    }
    if (lane == 63) wtot[wid] = s;
    // wave 0: block prefix (sum of bsum[0..blockIdx)) and grand total
    if (tid < 64) {
        int v   = (tid < B) ? bsum[tid] : 0;
        int pre = (tid < (int)blockIdx.x) ? v : 0;
        int tot = v;
#pragma unroll
        for (int off = 32; off > 0; off >>= 1) {
            pre += __shfl_xor(pre, off, 64);
            tot += __shfl_xor(tot, off, 64);
        }
        if (tid == 0) {
            sh_base = pre;
            if (blockIdx.x == 0) row_ptr[n] = tot;
        }
    }
    __syncthreads();
    int wpre = 0;
#pragma unroll
    for (int k = 0; k < 4; ++k) if (k < wid) wpre += wtot[k];
    int pre = sh_base + wpre + (s - tsum);
    if (i0 < n) {
        int4 e;
        e.x = pre;
        e.y = pre + dcnt[0];
        e.z = e.y + dcnt[1];
        e.w = e.z + dcnt[2];
        *(int4*)(row_ptr + i0) = e;
        int ev[4] = { e.x, e.y, e.z, e.w };
        float4 el;
        el.x = esum[0] / fmaxf((float)dcnt[0], 1.0f);
        el.y = esum[1] / fmaxf((float)dcnt[1], 1.0f);
        el.z = esum[2] / fmaxf((float)dcnt[2], 1.0f);
        el.w = esum[3] / fmaxf((float)dcnt[3], 1.0f);
        *(float4*)(ea_loop + i0) = el;
#pragma unroll
        for (int k = 0; k < 4; ++k) wptr_pad[(size_t)(i0 + k) * 16] = ev[k];
    }
}

// ---------------------------------------------------------------------------
// scatter edges into CSR order; (src,w) packed as int2.
// ---------------------------------------------------------------------------
__global__ void edge_scatter(const int* __restrict__ ei, const float* __restrict__ ea,
                             int* __restrict__ wptr_pad, int2* __restrict__ spk, int E) {
    int e = blockIdx.x * blockDim.x + threadIdx.x;
    if (e < E) {
        int d = ei[E + e];
        int pos = atomicAdd(&wptr_pad[(size_t)d * 16], 1);
        spk[pos] = make_int2(ei[e], __float_as_int(ea[e]));
    }
}

// ---------------------------------------------------------------------------
// bf16 MFMA GEMM + bias (B pre-transposed), 64x64 tile, BK=32.
// OUT_FP8: epilogue packs to fp8 (e4m3, hardware RNE) else bf16.
// ---------------------------------------------------------------------------
template <bool OUT_FP8>
__global__ void __launch_bounds__(256)
gemm_bf16(const unsigned short* __restrict__ A, const unsigned short* __restrict__ Bt,
          const float* __restrict__ bias, void* __restrict__ Cv,
          int M, int N, int K) {
    __shared__ __attribute__((aligned(16))) unsigned short As[64 * 40];
    __shared__ __attribute__((aligned(16))) unsigned short Bs[64 * 40];
    int tid  = threadIdx.x;
    int wave = tid >> 6, lane = tid & 63;
    int m0 = blockIdx.x * 64, n0 = blockIdx.y * 64;
    int row = tid >> 2, kg = (tid & 3) * 8;

    f32x4 acc[4] = {};
    for (int kk = 0; kk < K; kk += 32) {
        int gm = m0 + row;
        uint4 av;
        if (gm < M) av = *(const uint4*)(A + (size_t)gm * K + kk + kg);
        else        av = make_uint4(0, 0, 0, 0);
        *(uint4*)&As[row * 40 + kg] = av;
        uint4 bv = *(const uint4*)(Bt + (size_t)(n0 + row) * K + kk + kg);
        *(uint4*)&Bs[row * 40 + kg] = bv;
        __syncthreads();
        short8 a = *(const short8*)&As[(wave * 16 + (lane & 15)) * 40 + (lane >> 4) * 8];
#pragma unroll
        for (int g = 0; g < 4; ++g) {
            short8 b = *(const short8*)&Bs[(g * 16 + (lane & 15)) * 40 + (lane >> 4) * 8];
            acc[g] = __builtin_amdgcn_mfma_f32_16x16x32_bf16(a, b, acc[g], 0, 0, 0);
        }
        __syncthreads();
    }
#pragma unroll
    for (int g = 0; g < 4; ++g) {
        int col = n0 + g * 16 + (lane & 15);
        float bs = bias[col];
#pragma unroll
        for (int r = 0; r < 4; ++r) {
            int grow = m0 + wave * 16 + (lane >> 4) * 4 + r;
            if (grow < M) {
                float val = acc[g][r] + bs;
                if constexpr (OUT_FP8) {
                    ((unsigned char*)Cv)[(size_t)grow * N + col] = f2fp8(val);
                } else {
                    ((unsigned short*)Cv)[(size_t)grow * N + col] = (unsigned short)f2bf(val);
                }
            }
        }
    }
}

// ---------------------------------------------------------------------------
// helpers for gat_agg (fp8 gather, packed-f32 math)
// ---------------------------------------------------------------------------
template <int NG>
__device__ __forceinline__ void unp2(uint2 u, v2f* xf) {
    xf[0] = __builtin_amdgcn_cvt_pk_f32_fp8(u.x, false);
    xf[1] = __builtin_amdgcn_cvt_pk_f32_fp8(u.x, true);
    if constexpr (NG == 4) {
        xf[2] = __builtin_amdgcn_cvt_pk_f32_fp8(u.y, false);
        xf[3] = __builtin_amdgcn_cvt_pk_f32_fp8(u.y, true);
    }
}
// reduction over G lanes, confined within each 32-lane half-wave
template <int G>
__device__ __forceinline__ float grp_reduce32(float vs) {
    vs = dpp_add<0xB1>(vs);                               // xor 1
    if constexpr (G >= 4)  vs = dpp_add<0x4E>(vs);        // xor 2
    if constexpr (G >= 8)  vs = dpp_add<0x141>(vs);       // xor 4 (row_half_mirror)
    if constexpr (G >= 16) vs = dpp_add<0x140>(vs);       // xor 8 (row_mirror)
    if constexpr (G >= 32) {                              // xor 16 (within 32-group)
        int t = __builtin_amdgcn_ds_swizzle(__float_as_int(vs), 0x401F);
        vs += __int_as_float(t);
    }
    return vs;
}

// ---------------------------------------------------------------------------
// fused GATv2 gather(fp8) + score + softmax + aggregate + relu.
// TWO EDGES PER WAVE (lanes 0-31 edge A, 32-63 edge B), packed-f32 math.
// 4-DEEP mov-free gather pipeline: 8 pair-metas + 4 gathers in flight,
// 2-phase unrolled steady state (no register rotation movs).  All loads stay
// within [start,end): pipelined path gated at npair>=8 (cnt>=16).
// OUT_MODE 0: dense bf16 rows.
// OUT_MODE 1: LDS block-reduction (4 waves) then 128 atomics per BLOCK
//             (4x fewer atomics / HBM write-through than per-wave atomics).
// ---------------------------------------------------------------------------
template <int HC, int STRIDE, int C, int OUT_MODE>
__global__ void __launch_bounds__(256)
gat_agg(const unsigned char* __restrict__ xlr,
        const float* __restrict__ We, const float* __restrict__ att,
        const float* __restrict__ bias,
        const int* __restrict__ row_ptr, const int2* __restrict__ spk,
        const float* __restrict__ ea_loop,
        void* __restrict__ out, int n) {
    constexpr int NV = HC / 32;      // channels (bytes) per lane
    constexpr int NG = NV / 2;       // float2 groups per lane
    constexpr int G  = C / NV;       // lanes per head within a half-wave
    constexpr int SHIFT = (STRIDE == 512) ? 9 : 8;
    constexpr float K23 = 2.0f / 3.0f;
    __shared__ float red[4][128];    // OUT_MODE 1 block reduction
    int wave = threadIdx.x >> 6;
    int lane = threadIdx.x & 63;
    int node = blockIdx.x * 4 + wave;
    bool active = node < n;
    if (OUT_MODE == 0 && !active) return;
    unsigned int lo32 = (unsigned int)(lane & 31) * NV;   // channel/byte offset
    int half = lane >> 5;

    float vout[NV];
#pragma unroll
    for (int j = 0; j < NV; ++j) vout[j] = 0.0f;

    if (active) {
        auto ldd = [&](unsigned int off) -> uint2 {
            uint2 r;
            if constexpr (NV == 8) r = *(const uint2*)(xlr + off);
            else { r.x = *(const unsigned int*)(xlr + off); r.y = 0u; }
            return r;
        };
        auto gat = [&](int s) -> uint2 {
            return ldd(((unsigned int)s << SHIFT) + lo32);
        };

        v2f xr2[NG], We2[NG], att62[NG], o2[NG];
        unp2<NG>(ldd(((unsigned int)node << SHIFT) + HC + lo32), xr2);
#pragma unroll
        for (int g = 0; g < NG; ++g) {
            We2[g]   = *(const v2f*)(We  + lo32 + 2 * g);
            v2f a    = *(const v2f*)(att + lo32 + 2 * g);
            att62[g] = a * (0.6f * LOG2E);
            o2[g]    = v2f{0.0f, 0.0f};
        }
        float l = 0.0f;

        int start = __builtin_amdgcn_readfirstlane(row_ptr[node]);
        int end   = __builtin_amdgcn_readfirstlane(row_ptr[node + 1]);
        float ea_l = ea_loop[node];

        auto process = [&](uint2 du, float w, bool maskhi) {
            v2f xf[NG];
            unp2<NG>(du, xf);
            v2f w2 = {w, w};
            v2f vs6 = {0.0f, 0.0f};
            float vs4 = 0.0f;
#pragma unroll
            for (int g = 0; g < NG; ++g) {
                v2f t  = pk_fma(w2, We2[g], xr2[g]);     // xr + w*We
                v2f mm = pk_add(xf[g], t);               // xl[src] + xr + w*We
                vs6 = pk_fma(att62[g], mm, vs6);
                vs4 = fmaf(fabsf(mm.x), att62[g].x, vs4);   // abs = free modifier
                vs4 = fmaf(fabsf(mm.y), att62[g].y, vs4);
            }
            float vs = fmaf(K23, vs4, vs6.x + vs6.y);
            vs = grp_reduce32<G>(vs);
            float pr = fast_exp2(vs);
            if (maskhi && lane >= 32) pr = 0.0f;
            l += pr;
            v2f pr2 = {pr, pr};
#pragma unroll
            for (int g = 0; g < NG; ++g) o2[g] = pk_fma(xf[g], pr2, o2[g]);
        };
        auto W = [&](int2 s) -> float { return __int_as_float(s.y); };

        // ---- self-loop edge (both halves same edge; upper half masked) ----
        process(ldd(((unsigned int)node << SHIFT) + lo32), ea_l, true);

        // ---- real edges: pairs across half-waves, 4-deep pipeline ----
        int cnt = end - start;
        int npair = cnt >> 1;
        const int2* pp = spk + start + half;   // this half's stream (2 ints / pair)

        if (npair >= 8) {
            // prologue: metas for pairs 0..7, gathers for pairs 0..3
            int2 s0 = pp[0],  s1 = pp[2],  s2 = pp[4],  s3 = pp[6];
            int2 s4 = pp[8],  s5 = pp[10], s6 = pp[12], s7 = pp[14];
            uint2 g0 = gat(s0.x), g1 = gat(s1.x), g2 = gat(s2.x), g3 = gat(s3.x);
            int p = 0;
            for (; p + 16 <= npair; p += 8) {
                // phase 1: gathers p+4..p+7; metas p+8..p+11; process p..p+3
                uint2 h0 = gat(s4.x), h1 = gat(s5.x), h2 = gat(s6.x), h3 = gat(s7.x);
                float w0 = W(s0), w1 = W(s1), w2 = W(s2), w3 = W(s3);
                s0 = pp[2*(p+8)];  s1 = pp[2*(p+9)];
                s2 = pp[2*(p+10)]; s3 = pp[2*(p+11)];
                process(g0, w0, false); process(g1, w1, false);
                process(g2, w2, false); process(g3, w3, false);
                // phase 2: gathers p+8..p+11; metas p+12..p+15; process p+4..p+7
                g0 = gat(s0.x); g1 = gat(s1.x); g2 = gat(s2.x); g3 = gat(s3.x);
                float w4 = W(s4), w5 = W(s5), w6 = W(s6), w7 = W(s7);
                s4 = pp[2*(p+12)]; s5 = pp[2*(p+13)];
                s6 = pp[2*(p+14)]; s7 = pp[2*(p+15)];
                process(h0, w4, false); process(h1, w5, false);
                process(h2, w6, false); process(h3, w7, false);
            }
            // epilogue invariant: g0..g3 = gathers pairs p..p+3,
            // s0..s3 = metas pairs p..p+3, s4..s7 = metas pairs p+4..p+7,
            // remaining r = npair - p in [8, 15].
            uint2 h0 = gat(s4.x), h1 = gat(s5.x), h2 = gat(s6.x), h3 = gat(s7.x);
            process(g0, W(s0), false); process(g1, W(s1), false);
            process(g2, W(s2), false); process(g3, W(s3), false);
            process(h0, W(s4), false); process(h1, W(s5), false);
            process(h2, W(s6), false); process(h3, W(s7), false);
            for (int k = p + 8; k < npair; ++k) {
                int2 t = pp[2 * k];
                process(gat(t.x), W(t), false);
            }
        } else {
            for (int k = 0; k < npair; ++k) {
                int2 t = pp[2 * k];
                process(gat(t.x), W(t), false);
            }
        }
        if (cnt & 1) {   // odd tail edge: both halves same edge, upper masked
            int2 st = spk[end - 1];
            process(gat(st.x), W(st), true);
        }

        // ---- combine the two half-wave accumulators ----
        l += __shfl_xor(l, 32, 64);
#pragma unroll
        for (int g = 0; g < NG; ++g) {
            o2[g].x += __shfl_xor(o2[g].x, 32, 64);
            o2[g].y += __shfl_xor(o2[g].y, 32, 64);
        }
        float inv = 1.0f / (l + 1e-16f);

        if (lane < 32) {
#pragma unroll
            for (int g = 0; g < NG; ++g) {
                v2f b = *(const v2f*)(bias + lo32 + 2 * g);
                vout[2 * g]     = fmaxf(o2[g].x * inv + b.x, 0.0f);
                vout[2 * g + 1] = fmaxf(o2[g].y * inv + b.y, 0.0f);
            }
            if constexpr (OUT_MODE == 0) {
                unsigned short* op = (unsigned short*)out + (size_t)node * HC + lo32;
                if constexpr (NV == 8) {
                    uint4 t;
                    t.x = f2bf(vout[0]) | (f2bf(vout[1]) << 16);
                    t.y = f2bf(vout[2]) | (f2bf(vout[3]) << 16);
                    t.z = f2bf(vout[4]) | (f2bf(vout[5]) << 16);
                    t.w = f2bf(vout[6]) | (f2bf(vout[7]) << 16);
                    *(uint4*)op = t;
                } else {
                    uint2 t;
                    t.x = f2bf(vout[0]) | (f2bf(vout[1]) << 16);
                    t.y = f2bf(vout[2]) | (f2bf(vout[3]) << 16);
                    *(uint2*)op = t;
                }
            }
        }
    }

    if constexpr (OUT_MODE == 1) {
        // block-level pooling reduction: 4 waves -> LDS -> one atomic pass
        if (lane < 32) {
#pragma unroll
            for (int j = 0; j < NV; ++j) red[wave][lo32 + j] = vout[j];
        }
        __syncthreads();
        if (wave == 0) {
            int c = lane;   // channels c and c+64
            float a = red[0][c] + red[1][c] + red[2][c] + red[3][c];
            float b = red[0][c + 64] + red[1][c + 64] + red[2][c + 64] + red[3][c + 64];
            float* pacc = (float*)out + (size_t)(blockIdx.x & 255) * 128;
            atomicAdd(&pacc[c], a);
            atomicAdd(&pacc[c + 64], b);
        }
    }
}

// ---------------------------------------------------------------------------
// finish pooling, softmax over 128, sigmoid(alpha). 1024 threads.
// ---------------------------------------------------------------------------
__global__ void __launch_bounds__(1024)
pool_final(const float* __restrict__ partial, int nb,
           const float* __restrict__ alpha_in,
           float* __restrict__ out, int n) {
    __shared__ float acc[8][128];
    __shared__ float red[4];
    int t = threadIdx.x & 127;        // column
    int g = threadIdx.x >> 7;         // group 0..7
    float s = 0.0f;
    for (int b = g; b < nb; b += 8) s += partial[b * 128 + t];
    acc[g][t] = s;
    __syncthreads();
    if (threadIdx.x < 128) {
        float tot = 0.0f;
#pragma unroll
        for (int k = 0; k < 8; ++k) tot += acc[k][t];
        float mean = tot / (float)n;
        float mx = mean;
#pragma unroll
        for (int off = 32; off > 0; off >>= 1) mx = fmaxf(mx, __shfl_xor(mx, off, 64));
        if ((t & 63) == 0) red[t >> 6] = mx;
        __syncthreads();
        mx = fmaxf(red[0], red[1]);
        float ex = __expf(mean - mx);
        float sm = ex;
#pragma unroll
        for (int off = 32; off > 0; off >>= 1) sm += __shfl_xor(sm, off, 64);
        if ((t & 63) == 0) red[2 + (t >> 6)] = sm;
        __syncthreads();
        sm = red[2] + red[3];
        out[t] = ex / sm;
        if (t == 0) out[128] = 1.0f / (1.0f + __expf(-alpha_in[0]));
    }
}

// ---------------------------------------------------------------------------
extern "C" void kernel_launch(void* const* d_in, const int* in_sizes, int n_in,
                              void* d_out, int out_size, void* d_ws, size_t ws_size,
                              hipStream_t stream) {
    const float* x    = (const float*)d_in[0];
    const int*   ei   = (const int*)d_in[1];
    const float* ea   = (const float*)d_in[2];
    const float* W1l  = (const float*)d_in[3];
    const float* b1l  = (const float*)d_in[4];
    const float* W1r  = (const float*)d_in[5];
    const float* b1r  = (const float*)d_in[6];
    const float* We1  = (const float*)d_in[7];
    const float* att1 = (const float*)d_in[8];
    const float* bias1= (const float*)d_in[9];
    const float* W2l  = (const float*)d_in[10];
    const float* b2l  = (const float*)d_in[11];
    const float* W2r  = (const float*)d_in[12];
    const float* b2r  = (const float*)d_in[13];
    const float* We2  = (const float*)d_in[14];
    const float* att2 = (const float*)d_in[15];
    const float* bias2= (const float*)d_in[16];
    const float* alpha= (const float*)d_in[17];
    float* out = (float*)d_out;

    const int F = 128, HC1 = 256, HC2 = 128;
    const int n = in_sizes[0] / F;       // 20000
    const int E = in_sizes[1] / 2;       // 640000
    const int B = (n + 1023) / 1024;     // scan blocks

    char* ws = (char*)d_ws;
    size_t off = 0;
    auto alloc = [&](size_t bytes) { size_t p = off; off += (bytes + 255) & ~(size_t)255; return p; };

    unsigned long long* hist = (unsigned long long*)(ws + alloc((size_t)n * 8 * 8));  // padded x8
    int*   row_ptr = (int*)  (ws + alloc((size_t)(n + 1) * 4));
    int*   wptr    = (int*)  (ws + alloc((size_t)n * 16 * 4));                        // padded x16
    float* ea_loop = (float*)(ws + alloc((size_t)n * 4));
    int*   bsum    = (int*)  (ws + alloc(64 * 4));
    int2*  spk     = (int2*) (ws + alloc((size_t)E * 8));
    unsigned short* xb   = (unsigned short*)(ws + alloc((size_t)n * F * 2));
    unsigned short* Wt1  = (unsigned short*)(ws + alloc((size_t)F * (2 * HC1) * 2));
    unsigned short* Wt2  = (unsigned short*)(ws + alloc((size_t)HC1 * (2 * HC2) * 2));
    float* b1cat   = (float*)(ws + alloc((size_t)2 * HC1 * 4));
    float* b2cat   = (float*)(ws + alloc((size_t)2 * HC2 * 4));
    unsigned char* xlr1 = (unsigned char*)(ws + alloc((size_t)n * 2 * HC1));   // fp8
    unsigned short* h1  = (unsigned short*)(ws + alloc((size_t)n * HC1 * 2));  // bf16
    float* partial = (float*)(ws + alloc((size_t)256 * 128 * 4));
    unsigned char* xlr2 = xlr1;   // layer-2 fp8 projections alias layer-1 buffer
    const int NB_SLOTS = 256;

    (void)hipMemsetAsync(hist, 0, (size_t)n * 8 * 8, stream);
    (void)hipMemsetAsync(partial, 0, (size_t)NB_SLOTS * 128 * 4, stream);

    int tb = 256;
    {
        int nF4  = n * F / 4;
        int WTOT = 2 * F * HC1 + 2 * HC1 * HC2 + 2 * HC1 + 2 * HC2;
        int total = E + nF4 + WTOT;
        fused_prep<<<(total + tb - 1) / tb, tb, 0, stream>>>(
            ei, ea, hist, E, x, xb, nF4,
            W1l, W1r, W2l, W2r, b1l, b1r, b2l, b2r,
            Wt1, Wt2, b1cat, b2cat, F, HC1, HC2);
    }
    scan_a<<<B, 256, 0, stream>>>(hist, bsum, n);
    scan_c<<<B, 256, 0, stream>>>(hist, bsum, row_ptr, wptr, ea_loop, n, B);
    edge_scatter<<<(E + tb - 1) / tb, tb, 0, stream>>>(ei, ea, wptr, spk, E);

    // layer 1: merged GEMM [n,128]@[128,512] -> xlr1 (fp8, xl|xr rows)
    {
        dim3 grid((n + 63) / 64, (2 * HC1) / 64);
        gemm_bf16<true><<<grid, 256, 0, stream>>>(xb, Wt1, b1cat, xlr1, n, 2 * HC1, F);
    }
    gat_agg<256, 512, 32, 0><<<(n + 3) / 4, 256, 0, stream>>>(
        xlr1, We1, att1, bias1, row_ptr, spk, ea_loop, h1, n);

    // layer 2: merged GEMM [n,256]@[256,256] -> xlr2 (fp8)
    {
        dim3 grid((n + 63) / 64, (2 * HC2) / 64);
        gemm_bf16<true><<<grid, 256, 0, stream>>>(h1, Wt2, b2cat, xlr2, n, 2 * HC2, HC1);
    }
    // layer-2 gat with fused pooling (LDS block-reduce + per-block atomics)
    gat_agg<128, 256, 128, 1><<<(n + 3) / 4, 256, 0, stream>>>(
        xlr2, We2, att2, bias2, row_ptr, spk, ea_loop, partial, n);

    pool_final<<<1, 1024, 0, stream>>>(partial, NB_SLOTS, alpha, out, n);
}

// Round 5
// 273.935 us; speedup vs baseline: 1.0667x; 1.0190x over previous
//
#include <hip/hip_runtime.h>
#include <math.h>

#define NEG_SLOPE 0.2f
#define LOG2E 1.4426950408889634f

typedef __attribute__((ext_vector_type(8))) short short8;   // 8 bf16 (4 VGPRs)
typedef __attribute__((ext_vector_type(4))) float f32x4;
typedef __attribute__((ext_vector_type(2))) float v2f;

__device__ __forceinline__ int imin(int a, int b) { return a < b ? a : b; }

__device__ __forceinline__ unsigned int f2bf(float f) {
    unsigned int u = __float_as_uint(f);
    return (u + 0x7fffu + ((u >> 16) & 1u)) >> 16;   // RNE
}
__device__ __forceinline__ float fast_exp2(float x) {
#if __has_builtin(__builtin_amdgcn_exp2f)
    return __builtin_amdgcn_exp2f(x);
#else
    return exp2f(x);
#endif
}
// fp8 (OCP e4m3 on gfx950) hardware pack/unpack
__device__ __forceinline__ unsigned char f2fp8(float v) {
    return (unsigned char)(__builtin_amdgcn_cvt_pk_fp8_f32(v, v, 0, false) & 0xff);
}
template <int CTRL>
__device__ __forceinline__ float dpp_add(float v) {
    int t = __builtin_amdgcn_update_dpp(0, __float_as_int(v), CTRL, 0xF, 0xF, true);
    return v + __int_as_float(t);
}
// gfx90a+ packed-FP32 VALU (2 channels / instruction) — hipcc scalarizes
// float2 arithmetic, so force the pk forms via asm.
__device__ __forceinline__ v2f pk_fma(v2f a, v2f b, v2f c) {
    v2f d;
    asm("v_pk_fma_f32 %0, %1, %2, %3" : "=v"(d) : "v"(a), "v"(b), "v"(c));
    return d;
}
__device__ __forceinline__ v2f pk_add(v2f a, v2f b) {
    v2f d;
    asm("v_pk_add_f32 %0, %1, %2" : "=v"(d) : "v"(a), "v"(b));
    return d;
}

// ---------------------------------------------------------------------------
// Fused prep kernel: three disjoint index ranges in one launch.
//  [0, E)            : packed histogram (64-bit atomic, 64B-padded slots)
//  [E, E+nF4)        : x fp32 -> bf16 (vec4)
//  [E+nF4, ..+WTOT)  : weight transposes -> bf16 + bias concats
// ---------------------------------------------------------------------------
__global__ void fused_prep(const int* __restrict__ ei, const float* __restrict__ ea,
                           unsigned long long* __restrict__ hist, int E,
                           const float* __restrict__ x, unsigned short* __restrict__ xb, int nF4,
                           const float* __restrict__ W1l, const float* __restrict__ W1r,
                           const float* __restrict__ W2l, const float* __restrict__ W2r,
                           const float* __restrict__ b1l, const float* __restrict__ b1r,
                           const float* __restrict__ b2l, const float* __restrict__ b2r,
                           unsigned short* __restrict__ Wt1, unsigned short* __restrict__ Wt2,
                           float* __restrict__ b1cat, float* __restrict__ b2cat,
                           int F, int HC1, int HC2) {
    int i = blockIdx.x * blockDim.x + threadIdx.x;
    if (i < E) {
        int d = ei[E + i];
        long long fx = (long long)__float2int_rn(ea[i] * 65536.0f);
        unsigned long long v = ((unsigned long long)fx << 32) | 1ull;
        atomicAdd(&hist[(size_t)d * 8], v);
        return;
    }
    int j = i - E;
    if (j < nF4) {
        float4 v = ((const float4*)x)[j];
        uint2 r;
        r.x = f2bf(v.x) | (f2bf(v.y) << 16);
        r.y = f2bf(v.z) | (f2bf(v.w) << 16);
        ((uint2*)xb)[j] = r;
        return;
    }
    int k = j - nF4;
    int S1 = F * HC1, S2 = HC1 * HC2;
    if (k < S1) {
        int kk = k / HC1, nn = k - kk * HC1;
        Wt1[(size_t)nn * F + kk] = (unsigned short)f2bf(W1l[k]);
    } else if (k < 2 * S1) {
        int m = k - S1;
        int kk = m / HC1, nn = m - kk * HC1;
        Wt1[(size_t)(HC1 + nn) * F + kk] = (unsigned short)f2bf(W1r[m]);
    } else if (k < 2 * S1 + S2) {
        int m = k - 2 * S1;
        int kk = m / HC2, nn = m - kk * HC2;
        Wt2[(size_t)nn * HC1 + kk] = (unsigned short)f2bf(W2l[m]);
    } else if (k < 2 * S1 + 2 * S2) {
        int m = k - 2 * S1 - S2;
        int kk = m / HC2, nn = m - kk * HC2;
        Wt2[(size_t)(HC2 + nn) * HC1 + kk] = (unsigned short)f2bf(W2r[m]);
    } else if (k < 2 * S1 + 2 * S2 + 2 * HC1) {
        int m = k - 2 * S1 - 2 * S2;
        b1cat[m] = (m < HC1) ? b1l[m] : b1r[m - HC1];
    } else if (k < 2 * S1 + 2 * S2 + 2 * HC1 + 2 * HC2) {
        int m = k - 2 * S1 - 2 * S2 - 2 * HC1;
        b2cat[m] = (m < HC2) ? b2l[m] : b2r[m - HC2];
    }
}

// ---------------------------------------------------------------------------
// 2-phase parallel scan over hist (padded stride 8): scan_a computes raw
// block sums; scan_c derives its own prefix from bsum in-wave (scan_b folded).
// ---------------------------------------------------------------------------
__global__ void scan_a(const unsigned long long* __restrict__ hist, int* __restrict__ bsum, int n) {
    __shared__ int wred[4];
    int base = blockIdx.x * 1024;
    int tid = threadIdx.x;
    int s = 0;
#pragma unroll
    for (int k = 0; k < 4; ++k) {
        int i = base + tid + k * 256;
        if (i < n) s += (int)(hist[(size_t)i * 8] & 0xffffffffull);
    }
#pragma unroll
    for (int off = 32; off > 0; off >>= 1) s += __shfl_xor(s, off, 64);
    if ((tid & 63) == 0) wred[tid >> 6] = s;
    __syncthreads();
    if (tid == 0) bsum[blockIdx.x] = wred[0] + wred[1] + wred[2] + wred[3];
}

__global__ void scan_c(const unsigned long long* __restrict__ hist,
                       const int* __restrict__ bsum, int* __restrict__ row_ptr,
                       int* __restrict__ wptr_pad, float* __restrict__ ea_loop,
                       int n, int B) {
    __shared__ int wtot[4];
    __shared__ int sh_base;
    int tid = threadIdx.x;
    int wid = tid >> 6, lane = tid & 63;
    int i0 = blockIdx.x * 1024 + tid * 4;
    int dcnt[4]; float esum[4];
#pragma unroll
    for (int k = 0; k < 4; ++k) {
        if (i0 + k < n) {
            unsigned long long h = hist[(size_t)(i0 + k) * 8];
            dcnt[k] = (int)(h & 0xffffffffull);
            esum[k] = (float)((int)(h >> 32)) * (1.0f / 65536.0f);
        } else { dcnt[k] = 0; esum[k] = 0.0f; }
    }
    int tsum = dcnt[0] + dcnt[1] + dcnt[2] + dcnt[3];
    int s = tsum;
#pragma unroll
    for (int off = 1; off < 64; off <<= 1) {
        int t = __shfl_up(s, off, 64);
        if (lane >= off) s += t;
    }
    if (lane == 63) wtot[wid] = s;
    // wave 0: block prefix (sum of bsum[0..blockIdx)) and grand total
    if (tid < 64) {
        int v   = (tid < B) ? bsum[tid] : 0;
        int pre = (tid < (int)blockIdx.x) ? v : 0;
        int tot = v;
#pragma unroll
        for (int off = 32; off > 0; off >>= 1) {
            pre += __shfl_xor(pre, off, 64);
            tot += __shfl_xor(tot, off, 64);
        }
        if (tid == 0) {
            sh_base = pre;
            if (blockIdx.x == 0) row_ptr[n] = tot;
        }
    }
    __syncthreads();
    int wpre = 0;
#pragma unroll
    for (int k = 0; k < 4; ++k) if (k < wid) wpre += wtot[k];
    int pre = sh_base + wpre + (s - tsum);
    if (i0 < n) {
        int4 e;
        e.x = pre;
        e.y = pre + dcnt[0];
        e.z = e.y + dcnt[1];
        e.w = e.z + dcnt[2];
        *(int4*)(row_ptr + i0) = e;
        int ev[4] = { e.x, e.y, e.z, e.w };
        float4 el;
        el.x = esum[0] / fmaxf((float)dcnt[0], 1.0f);
        el.y = esum[1] / fmaxf((float)dcnt[1], 1.0f);
        el.z = esum[2] / fmaxf((float)dcnt[2], 1.0f);
        el.w = esum[3] / fmaxf((float)dcnt[3], 1.0f);
        *(float4*)(ea_loop + i0) = el;
#pragma unroll
        for (int k = 0; k < 4; ++k) wptr_pad[(size_t)(i0 + k) * 16] = ev[k];
    }
}

// ---------------------------------------------------------------------------
// scatter edges into CSR order; (src,w) packed as int2.
// ---------------------------------------------------------------------------
__global__ void edge_scatter(const int* __restrict__ ei, const float* __restrict__ ea,
                             int* __restrict__ wptr_pad, int2* __restrict__ spk, int E) {
    int e = blockIdx.x * blockDim.x + threadIdx.x;
    if (e < E) {
        int d = ei[E + e];
        int pos = atomicAdd(&wptr_pad[(size_t)d * 16], 1);
        spk[pos] = make_int2(ei[e], __float_as_int(ea[e]));
    }
}

// ---------------------------------------------------------------------------
// bf16 MFMA GEMM + bias (B pre-transposed), 64x64 tile, BK=32.
// OUT_FP8: epilogue packs to fp8 (e4m3, hardware RNE) else bf16.
// ---------------------------------------------------------------------------
template <bool OUT_FP8>
__global__ void __launch_bounds__(256)
gemm_bf16(const unsigned short* __restrict__ A, const unsigned short* __restrict__ Bt,
          const float* __restrict__ bias, void* __restrict__ Cv,
          int M, int N, int K) {
    __shared__ __attribute__((aligned(16))) unsigned short As[64 * 40];
    __shared__ __attribute__((aligned(16))) unsigned short Bs[64 * 40];
    int tid  = threadIdx.x;
    int wave = tid >> 6, lane = tid & 63;
    int m0 = blockIdx.x * 64, n0 = blockIdx.y * 64;
    int row = tid >> 2, kg = (tid & 3) * 8;

    f32x4 acc[4] = {};
    for (int kk = 0; kk < K; kk += 32) {
        int gm = m0 + row;
        uint4 av;
        if (gm < M) av = *(const uint4*)(A + (size_t)gm * K + kk + kg);
        else        av = make_uint4(0, 0, 0, 0);
        *(uint4*)&As[row * 40 + kg] = av;
        uint4 bv = *(const uint4*)(Bt + (size_t)(n0 + row) * K + kk + kg);
        *(uint4*)&Bs[row * 40 + kg] = bv;
        __syncthreads();
        short8 a = *(const short8*)&As[(wave * 16 + (lane & 15)) * 40 + (lane >> 4) * 8];
#pragma unroll
        for (int g = 0; g < 4; ++g) {
            short8 b = *(const short8*)&Bs[(g * 16 + (lane & 15)) * 40 + (lane >> 4) * 8];
            acc[g] = __builtin_amdgcn_mfma_f32_16x16x32_bf16(a, b, acc[g], 0, 0, 0);
        }
        __syncthreads();
    }
#pragma unroll
    for (int g = 0; g < 4; ++g) {
        int col = n0 + g * 16 + (lane & 15);
        float bs = bias[col];
#pragma unroll
        for (int r = 0; r < 4; ++r) {
            int grow = m0 + wave * 16 + (lane >> 4) * 4 + r;
            if (grow < M) {
                float val = acc[g][r] + bs;
                if constexpr (OUT_FP8) {
                    ((unsigned char*)Cv)[(size_t)grow * N + col] = f2fp8(val);
                } else {
                    ((unsigned short*)Cv)[(size_t)grow * N + col] = (unsigned short)f2bf(val);
                }
            }
        }
    }
}

// ---------------------------------------------------------------------------
// helpers for gat_agg (fp8 gather, packed-f32 math)
// ---------------------------------------------------------------------------
template <int NG>
__device__ __forceinline__ void unp2(uint2 u, v2f* xf) {
    xf[0] = __builtin_amdgcn_cvt_pk_f32_fp8(u.x, false);
    xf[1] = __builtin_amdgcn_cvt_pk_f32_fp8(u.x, true);
    if constexpr (NG == 4) {
        xf[2] = __builtin_amdgcn_cvt_pk_f32_fp8(u.y, false);
        xf[3] = __builtin_amdgcn_cvt_pk_f32_fp8(u.y, true);
    }
}
// reduction over G lanes, confined within each 32-lane half-wave
template <int G>
__device__ __forceinline__ float grp_reduce32(float vs) {
    vs = dpp_add<0xB1>(vs);                               // xor 1
    if constexpr (G >= 4)  vs = dpp_add<0x4E>(vs);        // xor 2
    if constexpr (G >= 8)  vs = dpp_add<0x141>(vs);       // xor 4 (row_half_mirror)
    if constexpr (G >= 16) vs = dpp_add<0x140>(vs);       // xor 8 (row_mirror)
    if constexpr (G >= 32) {                              // xor 16 (within 32-group)
        int t = __builtin_amdgcn_ds_swizzle(__float_as_int(vs), 0x401F);
        vs += __int_as_float(t);
    }
    return vs;
}

// ---------------------------------------------------------------------------
// fused GATv2 gather(fp8) + score + softmax + aggregate + relu.
// TWO EDGES PER WAVE (lanes 0-31 edge A, 32-63 edge B), packed-f32 math,
// and TWO WAVES PER NODE: wave sub=0 takes pairs [0,npair/2) + self-loop,
// sub=1 takes [npair/2,npair) + odd tail.  Partial (l, o) combined via LDS
// (one barrier).  Doubles independent waves (latency hiding via TLP, the
// R4 lesson: VGPR<64 matters more than pipeline depth) and halves the
// degree-imbalance tail.  Gather pipeline is the VGPR-lean 2-deep one.
// Block = 4 waves = 2 nodes; grid = ceil(n/2).
// OUT_MODE 0: dense bf16 rows.
// OUT_MODE 1: LDS block-reduction then 128 atomics per BLOCK.
// ---------------------------------------------------------------------------
template <int HC, int STRIDE, int C, int OUT_MODE>
__global__ void __launch_bounds__(256)
gat_agg(const unsigned char* __restrict__ xlr,
        const float* __restrict__ We, const float* __restrict__ att,
        const float* __restrict__ bias,
        const int* __restrict__ row_ptr, const int2* __restrict__ spk,
        const float* __restrict__ ea_loop,
        void* __restrict__ out, int n) {
    constexpr int NV = HC / 32;      // channels (bytes) per lane
    constexpr int NG = NV / 2;       // float2 groups per lane
    constexpr int G  = C / NV;       // lanes per head within a half-wave
    constexpr int SHIFT = (STRIDE == 512) ? 9 : 8;
    constexpr float K23 = 2.0f / 3.0f;
    __shared__ float lsh[2][32];     // sub1 partial softmax denom (per lane)
    __shared__ float osh[2][HC];     // sub1 partial aggregate
    __shared__ float red[2][128];    // OUT_MODE 1 block pooling reduction
    int wave = threadIdx.x >> 6;
    int lane = threadIdx.x & 63;
    int nib  = wave >> 1;            // node in block (0..1)
    int sub  = wave & 1;             // which half of the edge list
    int node = blockIdx.x * 2 + nib;
    bool active = node < n;
    unsigned int lo32 = (unsigned int)(lane & 31) * NV;   // channel/byte offset
    int half = lane >> 5;

    v2f o2[NG];
#pragma unroll
    for (int g = 0; g < NG; ++g) o2[g] = v2f{0.0f, 0.0f};
    float l = 0.0f;

    v2f xr2[NG], We2[NG], att62[NG];

    auto ldd = [&](unsigned int off) -> uint2 {
        uint2 r;
        if constexpr (NV == 8) r = *(const uint2*)(xlr + off);
        else { r.x = *(const unsigned int*)(xlr + off); r.y = 0u; }
        return r;
    };
    auto gat = [&](int s) -> uint2 {
        return ldd(((unsigned int)s << SHIFT) + lo32);
    };
    auto W = [&](int2 s) -> float { return __int_as_float(s.y); };

    if (active) {
        unp2<NG>(ldd(((unsigned int)node << SHIFT) + HC + lo32), xr2);
#pragma unroll
        for (int g = 0; g < NG; ++g) {
            We2[g]   = *(const v2f*)(We  + lo32 + 2 * g);
            v2f a    = *(const v2f*)(att + lo32 + 2 * g);
            att62[g] = a * (0.6f * LOG2E);
        }

        int start = __builtin_amdgcn_readfirstlane(row_ptr[node]);
        int end   = __builtin_amdgcn_readfirstlane(row_ptr[node + 1]);
        int cnt = end - start;
        int npair = cnt >> 1;

        auto process = [&](uint2 du, float w, bool maskhi) {
            v2f xf[NG];
            unp2<NG>(du, xf);
            v2f w2 = {w, w};
            v2f vs6 = {0.0f, 0.0f};
            float vs4 = 0.0f;
#pragma unroll
            for (int g = 0; g < NG; ++g) {
                v2f t  = pk_fma(w2, We2[g], xr2[g]);     // xr + w*We
                v2f mm = pk_add(xf[g], t);               // xl[src] + xr + w*We
                vs6 = pk_fma(att62[g], mm, vs6);
                vs4 = fmaf(fabsf(mm.x), att62[g].x, vs4);   // abs = free modifier
                vs4 = fmaf(fabsf(mm.y), att62[g].y, vs4);
            }
            float vs = fmaf(K23, vs4, vs6.x + vs6.y);
            vs = grp_reduce32<G>(vs);
            float pr = fast_exp2(vs);
            if (maskhi && lane >= 32) pr = 0.0f;
            l += pr;
            v2f pr2 = {pr, pr};
#pragma unroll
            for (int g = 0; g < NG; ++g) o2[g] = pk_fma(xf[g], pr2, o2[g]);
        };

        // this wave's pair range
        int lo = sub ? (npair >> 1) : 0;
        int hi = sub ? npair : (npair >> 1);
        int m = hi - lo;

        if (sub == 0) {
            // self-loop edge (both halves same edge; upper half masked)
            float ea_l = ea_loop[node];
            process(ldd(((unsigned int)node << SHIFT) + lo32), ea_l, true);
        }

        const int2* q = spk + start + half + 2 * lo;   // q[2k] = meta of pair lo+k
        if (m >= 2) {
            int2 sA = q[0], sB = q[2];
            uint2 gA = gat(sA.x);
            int p = 0;
            for (; p + 4 <= m; p += 2) {
                uint2 gB = gat(sB.x);
                int2 sC = q[2 * (p + 2)], sD = q[2 * (p + 3)];
                process(gA, W(sA), false);
                uint2 gC = gat(sC.x);
                process(gB, W(sB), false);
                sA = sC; sB = sD; gA = gC;
            }
            // m - p == 2 or 3; invariant: sA,sB metas p,p+1; gA gather of p
            uint2 gB = gat(sB.x);
            process(gA, W(sA), false);
            process(gB, W(sB), false);
            if (m - p == 3) {
                int2 t = q[2 * (p + 2)];
                process(gat(t.x), W(t), false);
            }
        } else if (m == 1) {
            int2 t = q[0];
            process(gat(t.x), W(t), false);
        }
        if (sub == 1 && (cnt & 1)) {   // odd tail edge; both halves same, upper masked
            int2 st = spk[end - 1];
            process(gat(st.x), W(st), true);
        }

        // ---- combine the two half-wave accumulators within the wave ----
        l += __shfl_xor(l, 32, 64);
#pragma unroll
        for (int g = 0; g < NG; ++g) {
            o2[g].x += __shfl_xor(o2[g].x, 32, 64);
            o2[g].y += __shfl_xor(o2[g].y, 32, 64);
        }
    }

    // ---- combine the two node-waves via LDS ----
    if (sub == 1 && lane < 32) {
        lsh[nib][lane] = l;
#pragma unroll
        for (int g = 0; g < NG; ++g) *(v2f*)&osh[nib][lo32 + 2 * g] = o2[g];
    }
    __syncthreads();

    float vout[NV];
#pragma unroll
    for (int j = 0; j < NV; ++j) vout[j] = 0.0f;

    if (sub == 0 && active && lane < 32) {
        l += lsh[nib][lane];
#pragma unroll
        for (int g = 0; g < NG; ++g) {
            v2f t = *(const v2f*)&osh[nib][lo32 + 2 * g];
            o2[g] = pk_add(o2[g], t);
        }
        float inv = 1.0f / (l + 1e-16f);
#pragma unroll
        for (int g = 0; g < NG; ++g) {
            v2f b = *(const v2f*)(bias + lo32 + 2 * g);
            vout[2 * g]     = fmaxf(o2[g].x * inv + b.x, 0.0f);
            vout[2 * g + 1] = fmaxf(o2[g].y * inv + b.y, 0.0f);
        }
        if constexpr (OUT_MODE == 0) {
            unsigned short* op = (unsigned short*)out + (size_t)node * HC + lo32;
            if constexpr (NV == 8) {
                uint4 t;
                t.x = f2bf(vout[0]) | (f2bf(vout[1]) << 16);
                t.y = f2bf(vout[2]) | (f2bf(vout[3]) << 16);
                t.z = f2bf(vout[4]) | (f2bf(vout[5]) << 16);
                t.w = f2bf(vout[6]) | (f2bf(vout[7]) << 16);
                *(uint4*)op = t;
            } else {
                uint2 t;
                t.x = f2bf(vout[0]) | (f2bf(vout[1]) << 16);
                t.y = f2bf(vout[2]) | (f2bf(vout[3]) << 16);
                *(uint2*)op = t;
            }
        }
    }

    if constexpr (OUT_MODE == 1) {
        // block-level pooling reduction: 2 nodes -> LDS -> one atomic pass
        if (sub == 0 && lane < 32) {
#pragma unroll
            for (int j = 0; j < NV; ++j) red[nib][lo32 + j] = vout[j];
        }
        __syncthreads();
        if (wave == 0) {
            int c = lane;   // channels c and c+64
            float a = red[0][c] + red[1][c];
            float b = red[0][c + 64] + red[1][c + 64];
            float* pacc = (float*)out + (size_t)(blockIdx.x & 255) * 128;
            atomicAdd(&pacc[c], a);
            atomicAdd(&pacc[c + 64], b);
        }
    }
}

// ---------------------------------------------------------------------------
// finish pooling, softmax over 128, sigmoid(alpha). 1024 threads.
// ---------------------------------------------------------------------------
__global__ void __launch_bounds__(1024)
pool_final(const float* __restrict__ partial, int nb,
           const float* __restrict__ alpha_in,
           float* __restrict__ out, int n) {
    __shared__ float acc[8][128];
    __shared__ float red[4];
    int t = threadIdx.x & 127;        // column
    int g = threadIdx.x >> 7;         // group 0..7
    float s = 0.0f;
    for (int b = g; b < nb; b += 8) s += partial[b * 128 + t];
    acc[g][t] = s;
    __syncthreads();
    if (threadIdx.x < 128) {
        float tot = 0.0f;
#pragma unroll
        for (int k = 0; k < 8; ++k) tot += acc[k][t];
        float mean = tot / (float)n;
        float mx = mean;
#pragma unroll
        for (int off = 32; off > 0; off >>= 1) mx = fmaxf(mx, __shfl_xor(mx, off, 64));
        if ((t & 63) == 0) red[t >> 6] = mx;
        __syncthreads();
        mx = fmaxf(red[0], red[1]);
        float ex = __expf(mean - mx);
        float sm = ex;
#pragma unroll
        for (int off = 32; off > 0; off >>= 1) sm += __shfl_xor(sm, off, 64);
        if ((t & 63) == 0) red[2 + (t >> 6)] = sm;
        __syncthreads();
        sm = red[2] + red[3];
        out[t] = ex / sm;
        if (t == 0) out[128] = 1.0f / (1.0f + __expf(-alpha_in[0]));
    }
}

// ---------------------------------------------------------------------------
extern "C" void kernel_launch(void* const* d_in, const int* in_sizes, int n_in,
                              void* d_out, int out_size, void* d_ws, size_t ws_size,
                              hipStream_t stream) {
    const float* x    = (const float*)d_in[0];
    const int*   ei   = (const int*)d_in[1];
    const float* ea   = (const float*)d_in[2];
    const float* W1l  = (const float*)d_in[3];
    const float* b1l  = (const float*)d_in[4];
    const float* W1r  = (const float*)d_in[5];
    const float* b1r  = (const float*)d_in[6];
    const float* We1  = (const float*)d_in[7];
    const float* att1 = (const float*)d_in[8];
    const float* bias1= (const float*)d_in[9];
    const float* W2l  = (const float*)d_in[10];
    const float* b2l  = (const float*)d_in[11];
    const float* W2r  = (const float*)d_in[12];
    const float* b2r  = (const float*)d_in[13];
    const float* We2  = (const float*)d_in[14];
    const float* att2 = (const float*)d_in[15];
    const float* bias2= (const float*)d_in[16];
    const float* alpha= (const float*)d_in[17];
    float* out = (float*)d_out;

    const int F = 128, HC1 = 256, HC2 = 128;
    const int n = in_sizes[0] / F;       // 20000
    const int E = in_sizes[1] / 2;       // 640000
    const int B = (n + 1023) / 1024;     // scan blocks

    char* ws = (char*)d_ws;
    size_t off = 0;
    auto alloc = [&](size_t bytes) { size_t p = off; off += (bytes + 255) & ~(size_t)255; return p; };

    unsigned long long* hist = (unsigned long long*)(ws + alloc((size_t)n * 8 * 8));  // padded x8
    int*   row_ptr = (int*)  (ws + alloc((size_t)(n + 1) * 4));
    int*   wptr    = (int*)  (ws + alloc((size_t)n * 16 * 4));                        // padded x16
    float* ea_loop = (float*)(ws + alloc((size_t)n * 4));
    int*   bsum    = (int*)  (ws + alloc(64 * 4));
    int2*  spk     = (int2*) (ws + alloc((size_t)E * 8));
    unsigned short* xb   = (unsigned short*)(ws + alloc((size_t)n * F * 2));
    unsigned short* Wt1  = (unsigned short*)(ws + alloc((size_t)F * (2 * HC1) * 2));
    unsigned short* Wt2  = (unsigned short*)(ws + alloc((size_t)HC1 * (2 * HC2) * 2));
    float* b1cat   = (float*)(ws + alloc((size_t)2 * HC1 * 4));
    float* b2cat   = (float*)(ws + alloc((size_t)2 * HC2 * 4));
    unsigned char* xlr1 = (unsigned char*)(ws + alloc((size_t)n * 2 * HC1));   // fp8
    unsigned short* h1  = (unsigned short*)(ws + alloc((size_t)n * HC1 * 2));  // bf16
    float* partial = (float*)(ws + alloc((size_t)256 * 128 * 4));
    unsigned char* xlr2 = xlr1;   // layer-2 fp8 projections alias layer-1 buffer
    const int NB_SLOTS = 256;

    (void)hipMemsetAsync(hist, 0, (size_t)n * 8 * 8, stream);
    (void)hipMemsetAsync(partial, 0, (size_t)NB_SLOTS * 128 * 4, stream);

    int tb = 256;
    {
        int nF4  = n * F / 4;
        int WTOT = 2 * F * HC1 + 2 * HC1 * HC2 + 2 * HC1 + 2 * HC2;
        int total = E + nF4 + WTOT;
        fused_prep<<<(total + tb - 1) / tb, tb, 0, stream>>>(
            ei, ea, hist, E, x, xb, nF4,
            W1l, W1r, W2l, W2r, b1l, b1r, b2l, b2r,
            Wt1, Wt2, b1cat, b2cat, F, HC1, HC2);
    }
    scan_a<<<B, 256, 0, stream>>>(hist, bsum, n);
    scan_c<<<B, 256, 0, stream>>>(hist, bsum, row_ptr, wptr, ea_loop, n, B);
    edge_scatter<<<(E + tb - 1) / tb, tb, 0, stream>>>(ei, ea, wptr, spk, E);

    // layer 1: merged GEMM [n,128]@[128,512] -> xlr1 (fp8, xl|xr rows)
    {
        dim3 grid((n + 63) / 64, (2 * HC1) / 64);
        gemm_bf16<true><<<grid, 256, 0, stream>>>(xb, Wt1, b1cat, xlr1, n, 2 * HC1, F);
    }
    gat_agg<256, 512, 32, 0><<<(n + 1) / 2, 256, 0, stream>>>(
        xlr1, We1, att1, bias1, row_ptr, spk, ea_loop, h1, n);

    // layer 2: merged GEMM [n,256]@[256,256] -> xlr2 (fp8)
    {
        dim3 grid((n + 63) / 64, (2 * HC2) / 64);
        gemm_bf16<true><<<grid, 256, 0, stream>>>(h1, Wt2, b2cat, xlr2, n, 2 * HC2, HC1);
    }
    // layer-2 gat with fused pooling (LDS block-reduce + per-block atomics)
    gat_agg<128, 256, 128, 1><<<(n + 1) / 2, 256, 0, stream>>>(
        xlr2, We2, att2, bias2, row_ptr, spk, ea_loop, partial, n);

    pool_final<<<1, 1024, 0, stream>>>(partial, NB_SLOTS, alpha, out, n);
}